// Round 1
// 1607.211 us; speedup vs baseline: 1.0499x; 1.0499x over previous
//
#include <hip/hip_runtime.h>
#include <math.h>

// B=128 S=512 D=1024 P=32 TEMP=0.1 BETA=0.4
// GEMM2 (x_rt = tail + h@wf2 + bf2) ELIMINATED algebraically:
//   scores = tail.qk + h.(wf2@qk) + bf2.qk + bk.qc     (wq2 = qk @ wf2^T precomputed)
//   ctx_rt = gather_a(tail) + gather_a(h) @ wf2 + asum*bf2   (only 32 rows/b survive top-k)
// Big GEMM1 bf16 MFMA m97-style; XCD-aware swizzle; LDS-staged epilogue.

typedef short bf16x8 __attribute__((ext_vector_type(8)));
typedef float f32x4 __attribute__((ext_vector_type(4)));

typedef const __attribute__((address_space(1))) void* gp_t;
typedef __attribute__((address_space(3))) void* lp_t;

__device__ __forceinline__ void ld16(const void* g, void* l) {
  __builtin_amdgcn_global_load_lds((gp_t)g, (lp_t)l, 16, 0, 0);
}

__device__ __forceinline__ unsigned int f2b(float f) {
  unsigned int u = __builtin_bit_cast(unsigned int, f);
  u = (u + 0x7FFFu + ((u >> 16) & 1u)) >> 16;   // RNE
  return u & 0xFFFFu;
}
__device__ __forceinline__ float b2f(unsigned short s) {
  unsigned int u = ((unsigned int)s) << 16;
  return __builtin_bit_cast(float, u);
}
__device__ __forceinline__ float b2f_lo(unsigned int u) { return __builtin_bit_cast(float, u << 16); }
__device__ __forceinline__ float b2f_hi(unsigned int u) { return __builtin_bit_cast(float, u & 0xFFFF0000u); }
__device__ __forceinline__ unsigned int pack2(float lo, float hi) { return f2b(lo) | (f2b(hi) << 16); }

// ---- fp32 -> bf16 convert of concat([tail, rel]) into feat [65536][2048], 16B ld/st ----
__global__ void cvt_feat_k(const float4* __restrict__ tail, const float4* __restrict__ rel,
                           uint4* __restrict__ feat) {
  unsigned i = blockIdx.x * 256 + threadIdx.x;     // one 8-elem bf16 chunk each; 16.7M total
  unsigned row = i >> 8, c = i & 255u;             // 256 chunks per feat row
  bool isrel = c >= 128u;
  const float4* src = isrel ? rel : tail;
  unsigned s = row * 256u + (c & 127u) * 2u;
  float4 a = src[s], b = src[s + 1];
  uint4 o;
  o.x = pack2(a.x, a.y); o.y = pack2(a.z, a.w);
  o.z = pack2(b.x, b.y); o.w = pack2(b.z, b.w);
  feat[i] = o;
}

// ---- W [K][N] fp32 -> Wt [N][K] bf16 (tiled transpose) ----
__global__ void transpose_cvt_k(const float* __restrict__ W, unsigned short* __restrict__ Wt,
                                int K, int N) {
  __shared__ float tile[32][33];
  int t = threadIdx.x;
  int tx = t & 31, ty = t >> 5;
  int n0 = blockIdx.x * 32, k0 = blockIdx.y * 32;
  #pragma unroll
  for (int i = 0; i < 32; i += 8)
    tile[ty + i][tx] = W[(size_t)(k0 + ty + i) * N + n0 + tx];
  __syncthreads();
  #pragma unroll
  for (int i = 0; i < 32; i += 8)
    Wt[(size_t)(n0 + ty + i) * K + k0 + tx] = (unsigned short)f2b(tile[tx][ty + i]);
}

// ---- small fp32 GEMM, M=128 fixed, N=1024, K-split over grid.y, atomic accumulate ----
// C[m][n] += sum_k (A[m][k] + A2[m][k] + rs[m]*u[k]) * (transB ? W[n][k] : W[k][n])
struct SJob { const float* A; const float* W; const float* u; const float* rs;
              const float* A2; float* C; int transB; int pad; };
struct SJobs { SJob j[6]; };

__global__ __launch_bounds__(256) void sgemm_k(SJobs jobs, int K) {
  SJob jb = jobs.j[blockIdx.z];
  __shared__ float At[32 * 132];   // [k][m]
  __shared__ float Wt_[32 * 36];   // [k][n]
  int t = threadIdx.x;
  int n0 = blockIdx.x * 32;
  int kchunk = K / gridDim.y;
  int kbase = blockIdx.y * kchunk;
  int tn = t & 7, tm = t >> 3;
  float acc[4][4] = {};
  for (int kt = 0; kt < kchunk; kt += 32) {
    int k0 = kbase + kt;
    #pragma unroll
    for (int i = 0; i < 16; ++i) {
      int f = i * 256 + t;
      int r = f >> 5, c = f & 31;
      float v = jb.A[(size_t)r * K + k0 + c];
      if (jb.A2) v += jb.A2[(size_t)r * K + k0 + c];
      if (jb.u) v += (jb.rs ? jb.rs[r] : 1.0f) * jb.u[k0 + c];
      At[c * 132 + r] = v;
    }
    #pragma unroll
    for (int i = 0; i < 4; ++i) {
      int f = i * 256 + t;
      if (!jb.transB) { int k = f >> 5, n = f & 31; Wt_[k * 36 + n] = jb.W[(size_t)(k0 + k) * 1024 + n0 + n]; }
      else            { int n = f >> 5, k = f & 31; Wt_[k * 36 + n] = jb.W[(size_t)(n0 + n) * K + k0 + k]; }
    }
    __syncthreads();
    #pragma unroll
    for (int kk = 0; kk < 32; ++kk) {
      float4 av = *(const float4*)&At[kk * 132 + tm * 4];
      float4 wv4 = *(const float4*)&Wt_[kk * 36 + tn * 4];
      float ar[4] = {av.x, av.y, av.z, av.w};
      float wr[4] = {wv4.x, wv4.y, wv4.z, wv4.w};
      #pragma unroll
      for (int r = 0; r < 4; ++r)
        #pragma unroll
        for (int c = 0; c < 4; ++c) acc[r][c] += ar[r] * wr[c];
    }
    __syncthreads();
  }
  #pragma unroll
  for (int r = 0; r < 4; ++r)
    #pragma unroll
    for (int c = 0; c < 4; ++c)
      atomicAdd(jb.C + (size_t)(tm * 4 + r) * 1024 + n0 + tn * 4 + c, acc[r][c]);
}

// ---- elementwise: qc = 0.3125*(0.4*iq+0.6*hq); pout = text*sig(tg)+img*sig(ig) ----
__global__ void ew1_k(const float* __restrict__ riq, const float* __restrict__ rhq,
                      const float* __restrict__ rt, const float* __restrict__ ri,
                      const float* __restrict__ rtg, const float* __restrict__ rig,
                      const float* __restrict__ biq, const float* __restrict__ bhq,
                      const float* __restrict__ blt, const float* __restrict__ bli,
                      const float* __restrict__ bgt, const float* __restrict__ bgi,
                      float* __restrict__ qc, float* __restrict__ pout) {
  int idx = blockIdx.x * 256 + threadIdx.x;
  int n = idx & 1023;
  float iq = riq[idx] + biq[n];
  float hq = rhq[idx] + bhq[n];
  qc[idx] = 0.3125f * (0.4f * iq + 0.6f * hq);
  float tg = 1.0f / (1.0f + expf(-(rtg[idx] + bgt[n])));
  float ig = 1.0f / (1.0f + expf(-(rig[idx] + bgi[n])));
  pout[idx] = (rt[idx] + blt[n]) * tg + (ri[idx] + bli[n]) * ig;
}

// ---- cv[b] = qc[b]·bk + qk[b]·bf2 ----
__global__ void cvec_k(const float* __restrict__ qc, const float* __restrict__ bk,
                       const float* __restrict__ qk, const float* __restrict__ bf2,
                       float* __restrict__ cv) {
  int b = blockIdx.x, l = threadIdx.x;  // 64 threads
  const float4* a = (const float4*)(qc + (size_t)b * 1024);
  const float4* k4 = (const float4*)bk;
  const float4* a2 = (const float4*)(qk + (size_t)b * 1024);
  const float4* k42 = (const float4*)bf2;
  float acc = 0.f;
  #pragma unroll
  for (int i = 0; i < 4; ++i) {
    float4 x = a[l + i * 64], y = k4[l + i * 64];
    acc += x.x * y.x + x.y * y.y + x.z * y.z + x.w * y.w;
    float4 x2 = a2[l + i * 64], y2 = k42[l + i * 64];
    acc += x2.x * y2.x + x2.y * y2.y + x2.z * y2.z + x2.w * y2.w;
  }
  for (int off = 32; off > 0; off >>= 1) acc += __shfl_down(acc, off);
  if (l == 0) cv[b] = acc;
}

// ---- big bf16 MFMA GEMM: C = act(A @ Wt^T + bias) (+resid), A[M][K], Wt[N][K], bf16 out ----
__global__ __launch_bounds__(256) void gemm_bf16_k(
    const unsigned short* __restrict__ A, const unsigned short* __restrict__ Wt,
    const float* __restrict__ bias, const float* __restrict__ resid,
    unsigned short* __restrict__ C, int M, int N, int K, int act) {
  __shared__ __align__(16) unsigned short Sm[16384];   // As[4096] | Bs[4096], reused as Cs[16384]
  unsigned short* As = Sm;
  unsigned short* Bs = Sm + 4096;
  int t = threadIdx.x;
  int l = t & 63, w = t >> 6;

  int L = blockIdx.x;
  int xcd = L & 7, j = L >> 3;
  int n_t = j & 7;
  int m_t = (j >> 3) * 8 + xcd;
  int m0 = m_t * 128, n0 = n_t * 128;
  int wm = (w >> 1) * 64, wn = (w & 1) * 64;

  int srow = t >> 2;
  int scol = ((t & 3) ^ ((t >> 3) & 3)) * 8;
  const unsigned short* Ag = A + (size_t)(m0 + srow) * K + scol;
  const unsigned short* Bg = Wt + (size_t)(n0 + srow) * K + scol;
  unsigned short* AsP = As + t * 8;
  unsigned short* BsP = Bs + t * 8;
  size_t rowadv = (size_t)64 * K;

  int lm = l & 15, q = l >> 4;
  int aoff[4], boff[4];
  #pragma unroll
  for (int i = 0; i < 4; ++i) {
    int ra = wm + i * 16 + lm;
    aoff[i] = ra * 32 + ((q ^ ((ra >> 1) & 3)) * 8);
    int rb = wn + i * 16 + lm;
    boff[i] = rb * 32 + ((q ^ ((rb >> 1) & 3)) * 8);
  }

  f32x4 acc[4][4];
  #pragma unroll
  for (int i = 0; i < 4; ++i)
    #pragma unroll
    for (int jj = 0; jj < 4; ++jj) acc[i][jj] = (f32x4){0.f, 0.f, 0.f, 0.f};

  int kiters = K >> 5;
  for (int kt = 0; kt < kiters; ++kt) {
    const unsigned short* a0 = Ag + kt * 32;
    const unsigned short* b0 = Bg + kt * 32;
    ld16(a0, AsP);
    ld16(a0 + rowadv, AsP + 2048);
    ld16(b0, BsP);
    ld16(b0 + rowadv, BsP + 2048);
    __syncthreads();
    bf16x8 af[4], bfv[4];
    #pragma unroll
    for (int i = 0; i < 4; ++i) af[i] = *(const bf16x8*)(As + aoff[i]);
    #pragma unroll
    for (int i = 0; i < 4; ++i) bfv[i] = *(const bf16x8*)(Bs + boff[i]);
    #pragma unroll
    for (int mi = 0; mi < 4; ++mi)
      #pragma unroll
      for (int ni = 0; ni < 4; ++ni)
        acc[mi][ni] = __builtin_amdgcn_mfma_f32_16x16x32_bf16(af[mi], bfv[ni], acc[mi][ni], 0, 0, 0);
    __syncthreads();
  }

  int lr = q * 4;
  #pragma unroll
  for (int mi = 0; mi < 4; ++mi) {
    #pragma unroll
    for (int ni = 0; ni < 4; ++ni) {
      int cn = wn + ni * 16 + lm;
      float bb = bias ? bias[n0 + cn] : 0.f;
      #pragma unroll
      for (int r = 0; r < 4; ++r) {
        int cm = wm + mi * 16 + lr + r;
        float v = acc[mi][ni][r] + bb;
        if (act == 1) v = v > 0.f ? v : 0.01f * v;   // leaky_relu 0.01
        Sm[cm * 128 + cn] = (unsigned short)f2b(v);
      }
    }
  }
  __syncthreads();

  #pragma unroll
  for (int p = 0; p < 8; ++p) {
    int idx = p * 256 + t;
    int row = idx >> 4;
    int col8 = (idx & 15) * 8;
    uint4 cs = *(const uint4*)(Sm + row * 128 + col8);
    size_t go = (size_t)(m0 + row) * N + n0 + col8;
    uint4 o;
    if (resid) {
      float4 r0 = *(const float4*)(resid + go);
      float4 r1 = *(const float4*)(resid + go + 4);
      o.x = pack2(b2f_lo(cs.x) + r0.x, b2f_hi(cs.x) + r0.y);
      o.y = pack2(b2f_lo(cs.y) + r0.z, b2f_hi(cs.y) + r0.w);
      o.z = pack2(b2f_lo(cs.z) + r1.x, b2f_hi(cs.z) + r1.y);
      o.w = pack2(b2f_lo(cs.w) + r1.z, b2f_hi(cs.w) + r1.w);
    } else {
      o = cs;
    }
    *(uint4*)(C + go) = o;
  }
}

// ---- scores[b,s] = valid ? tail_bf16[b,s]·qk[b] + h[b,s]·wq2[b] + cv[b] : -inf ----
// tail bf16 lives in the first half of each feat row (stride 2048).
__global__ void scores_k(const unsigned short* __restrict__ feat, const unsigned short* __restrict__ h,
                         const float* __restrict__ qk, const float* __restrict__ wq2,
                         const float* __restrict__ cv, const float* __restrict__ mask,
                         float* __restrict__ sc) {
  int w = threadIdx.x >> 6, l = threadIdx.x & 63;
  int row = blockIdx.x * 4 + w;
  int b = row >> 9;
  const uint4* tp = (const uint4*)(feat + (size_t)row * 2048);   // first 128 uint4 = tail half
  const uint4* hp = (const uint4*)(h + (size_t)row * 1024);
  const float4* qp = (const float4*)(qk + (size_t)b * 1024);
  const float4* wp_ = (const float4*)(wq2 + (size_t)b * 1024);
  float acc = 0.f;
  #pragma unroll
  for (int i = 0; i < 2; ++i) {
    uint4 xa = tp[l * 2 + i];
    float4 q0 = qp[l * 4 + i * 2];
    float4 q1 = qp[l * 4 + i * 2 + 1];
    acc += b2f_lo(xa.x) * q0.x + b2f_hi(xa.x) * q0.y;
    acc += b2f_lo(xa.y) * q0.z + b2f_hi(xa.y) * q0.w;
    acc += b2f_lo(xa.z) * q1.x + b2f_hi(xa.z) * q1.y;
    acc += b2f_lo(xa.w) * q1.z + b2f_hi(xa.w) * q1.w;
    uint4 ha = hp[l * 2 + i];
    float4 w0 = wp_[l * 4 + i * 2];
    float4 w1 = wp_[l * 4 + i * 2 + 1];
    acc += b2f_lo(ha.x) * w0.x + b2f_hi(ha.x) * w0.y;
    acc += b2f_lo(ha.y) * w0.z + b2f_hi(ha.y) * w0.w;
    acc += b2f_lo(ha.z) * w1.x + b2f_hi(ha.z) * w1.y;
    acc += b2f_lo(ha.w) * w1.z + b2f_hi(ha.w) * w1.w;
  }
  for (int off = 32; off > 0; off >>= 1) acc += __shfl_down(acc, off);
  if (l == 0) sc[row] = (mask[row] > 0.01f) ? (acc + cv[b]) : -__builtin_inff();
}

// ---- per-b softmax, top-32 (no renorm); gather ctxtail = sum a*tail_f32, gh = sum a*h, asum ----
__global__ __launch_bounds__(256) void topk_ctx_k(const float* __restrict__ sc,
                                                  const float* __restrict__ xtail,
                                                  const unsigned short* __restrict__ h,
                                                  float* __restrict__ ctxtail, float* __restrict__ gh,
                                                  float* __restrict__ asum) {
  int b = blockIdx.x, t = threadIdx.x;
  __shared__ float sv[512];
  __shared__ float red[256];
  __shared__ int redi[256];
  __shared__ float topw[32];
  __shared__ int topi[32];
  sv[t] = sc[b * 512 + t];
  sv[t + 256] = sc[b * 512 + 256 + t];
  __syncthreads();
  red[t] = fmaxf(sv[t], sv[t + 256]);
  __syncthreads();
  for (int s = 128; s > 0; s >>= 1) { if (t < s) red[t] = fmaxf(red[t], red[t + s]); __syncthreads(); }
  float mx = red[0];
  __syncthreads();
  float e0 = expf(sv[t] - mx), e1 = expf(sv[t + 256] - mx);
  red[t] = e0 + e1;
  __syncthreads();
  for (int s = 128; s > 0; s >>= 1) { if (t < s) red[t] += red[t + s]; __syncthreads(); }
  float inv = 1.0f / red[0];
  __syncthreads();
  sv[t] = e0 * inv; sv[t + 256] = e1 * inv;
  __syncthreads();
  for (int it = 0; it < 32; ++it) {
    float v0 = sv[t], v1 = sv[t + 256];
    float bv_; int bi;
    if (v1 > v0) { bv_ = v1; bi = t + 256; } else { bv_ = v0; bi = t; }
    red[t] = bv_; redi[t] = bi;
    __syncthreads();
    for (int s = 128; s > 0; s >>= 1) {
      if (t < s) {
        if (red[t + s] > red[t] || (red[t + s] == red[t] && redi[t + s] < redi[t])) {
          red[t] = red[t + s]; redi[t] = redi[t + s];
        }
      }
      __syncthreads();
    }
    if (t == 0) { topw[it] = red[0]; topi[it] = redi[0]; sv[redi[0]] = -1.0f; }
    __syncthreads();
  }
  #pragma unroll
  for (int dd = 0; dd < 4; ++dd) {
    int d = t + dd * 256;
    float at = 0.f, ah = 0.f;
    for (int j = 0; j < 32; ++j) {
      size_t ro = (size_t)(b * 512 + topi[j]) * 1024 + d;
      at += topw[j] * xtail[ro];
      ah += topw[j] * b2f(h[ro]);
    }
    ctxtail[(size_t)b * 1024 + d] = at;
    gh[(size_t)b * 1024 + d] = ah;
  }
  if (t == 0) {
    float s = 0.f;
    for (int j = 0; j < 32; ++j) s += topw[j];
    asum[b] = s;
  }
}

// ---- out = rawL3 + bltr + pout ----
__global__ void ew2_k(const float* __restrict__ r3, const float* __restrict__ bltr,
                      const float* __restrict__ pout, float* __restrict__ out) {
  int idx = blockIdx.x * 256 + threadIdx.x;
  out[idx] = r3[idx] + bltr[idx & 1023] + pout[idx];
}

extern "C" void kernel_launch(void* const* d_in, const int* in_sizes, int n_in,
                              void* d_out, int out_size, void* d_ws, size_t ws_size,
                              hipStream_t stream) {
  const float* x_head = (const float*)d_in[0];
  const float* x_rel  = (const float*)d_in[1];
  const float* x_tail = (const float*)d_in[2];
  const float* x_mask = (const float*)d_in[3];
  const float* x_img  = (const float*)d_in[4];
  const float* wf1 = (const float*)d_in[5];  const float* bf1 = (const float*)d_in[6];
  const float* wf2 = (const float*)d_in[7];  const float* bf2 = (const float*)d_in[8];
  const float* wk  = (const float*)d_in[9];  const float* bk  = (const float*)d_in[10];
  const float* wv  = (const float*)d_in[11]; const float* bv  = (const float*)d_in[12];
  const float* wp  = (const float*)d_in[13]; const float* bp  = (const float*)d_in[14];
  const float* wiq = (const float*)d_in[15]; const float* biq = (const float*)d_in[16];
  const float* whq = (const float*)d_in[17]; const float* bhq = (const float*)d_in[18];
  const float* wlt = (const float*)d_in[19]; const float* blt = (const float*)d_in[20];
  const float* wli = (const float*)d_in[21]; const float* bli = (const float*)d_in[22];
  const float* wltr= (const float*)d_in[23]; const float* bltr= (const float*)d_in[24];
  const float* wgt = (const float*)d_in[25]; const float* bgt = (const float*)d_in[26];
  const float* wgi = (const float*)d_in[27]; const float* bgi = (const float*)d_in[28];
  float* out = (float*)d_out;
  char* ws = (char*)d_ws;

  // workspace layout (bytes)
  unsigned short* feat = (unsigned short*)(ws);                       // 268435456 (stays live)
  unsigned short* hbuf = (unsigned short*)(ws + 268435456ull);        // 134217728
  unsigned short* wf1t = (unsigned short*)(ws + 402653184ull);        // 4194304
  char* z = ws + 406847488ull;                                        // 12 x 512KB zeroed
  float* raw_iq = (float*)(z);
  float* raw_hq = (float*)(z + 524288);
  float* raw_t  = (float*)(z + 1048576);
  float* raw_i  = (float*)(z + 1572864);
  float* raw_tg = (float*)(z + 2097152);
  float* raw_ig = (float*)(z + 2621440);
  float* raw_q  = (float*)(z + 3145728);      // qk = wk @ qc
  float* wq2    = (float*)(z + 3670016);      // qk @ wf2^T
  float* rawG   = (float*)(z + 4194304);      // gh @ wf2
  float* rawL1  = (float*)(z + 4718592);
  float* rawL2  = (float*)(z + 5242880);
  float* rawL3  = (float*)(z + 5767168);
  float* qc      = (float*)(ws + 413138944ull);
  float* pout    = (float*)(ws + 413663232ull);
  float* cv      = (float*)(ws + 414187520ull);
  float* sc      = (float*)(ws + 414191616ull);
  float* ctxtail = (float*)(ws + 414453760ull);
  float* gh      = (float*)(ws + 414978048ull);
  float* asum    = (float*)(ws + 415502336ull);

  hipMemsetAsync(z, 0, 6291456, stream);

  cvt_feat_k<<<65536, 256, 0, stream>>>((const float4*)x_tail, (const float4*)x_rel, (uint4*)feat);
  transpose_cvt_k<<<dim3(32, 64), 256, 0, stream>>>(wf1, wf1t, 2048, 1024);

  SJobs j6 = {};
  j6.j[0] = SJob{x_img,  wiq, nullptr, nullptr, nullptr, raw_iq, 0, 0};
  j6.j[1] = SJob{x_head, whq, nullptr, nullptr, nullptr, raw_hq, 0, 0};
  j6.j[2] = SJob{x_head, wlt, nullptr, nullptr, nullptr, raw_t,  0, 0};
  j6.j[3] = SJob{x_img,  wli, nullptr, nullptr, nullptr, raw_i,  0, 0};
  j6.j[4] = SJob{x_head, wgt, nullptr, nullptr, nullptr, raw_tg, 0, 0};
  j6.j[5] = SJob{x_img,  wgi, nullptr, nullptr, nullptr, raw_ig, 0, 0};
  sgemm_k<<<dim3(32, 2, 6), 256, 0, stream>>>(j6, 1024);

  ew1_k<<<512, 256, 0, stream>>>(raw_iq, raw_hq, raw_t, raw_i, raw_tg, raw_ig,
                                 biq, bhq, blt, bli, bgt, bgi, qc, pout);

  SJobs jq = {};
  jq.j[0] = SJob{qc, wk, nullptr, nullptr, nullptr, raw_q, 1, 0};   // qk = qc @ wk^T
  sgemm_k<<<dim3(32, 4, 1), 256, 0, stream>>>(jq, 1024);
  jq.j[0] = SJob{raw_q, wf2, nullptr, nullptr, nullptr, wq2, 1, 0}; // wq2 = qk @ wf2^T
  sgemm_k<<<dim3(32, 4, 1), 256, 0, stream>>>(jq, 1024);
  cvec_k<<<128, 64, 0, stream>>>(qc, bk, raw_q, bf2, cv);           // cv = qc·bk + qk·bf2

  // h = leaky(feat @ wf1 + bf1)
  gemm_bf16_k<<<4096, 256, 0, stream>>>(feat, wf1t, bf1, nullptr, hbuf, 65536, 1024, 2048, 1);

  scores_k<<<16384, 256, 0, stream>>>(feat, hbuf, raw_q, wq2, cv, x_mask, sc);
  topk_ctx_k<<<128, 256, 0, stream>>>(sc, x_tail, hbuf, ctxtail, gh, asum);

  SJobs jl = {};
  jl.j[0] = SJob{gh, wf2, nullptr, nullptr, nullptr, rawG, 0, 0};        // gh @ wf2
  sgemm_k<<<dim3(32, 4, 1), 256, 0, stream>>>(jl, 1024);
  jl.j[0] = SJob{rawG, wv, bf2, asum, ctxtail, rawL1, 0, 0};             // (ctx_rt) @ wv
  sgemm_k<<<dim3(32, 4, 1), 256, 0, stream>>>(jl, 1024);
  jl.j[0] = SJob{rawL1, wp, bv, asum, nullptr, rawL2, 0, 0};             // (+asum*bv) @ wp
  sgemm_k<<<dim3(32, 4, 1), 256, 0, stream>>>(jl, 1024);
  jl.j[0] = SJob{rawL2, wltr, bp, nullptr, nullptr, rawL3, 0, 0};        // (+bp) @ wltr
  sgemm_k<<<dim3(32, 4, 1), 256, 0, stream>>>(jl, 1024);
  ew2_k<<<512, 256, 0, stream>>>(rawL3, bltr, pout, out);
}

// Round 2
// 1446.172 us; speedup vs baseline: 1.1668x; 1.1114x over previous
//
#include <hip/hip_runtime.h>
#include <math.h>

// B=128 S=512 D=1024 P=32 TEMP=0.1 BETA=0.4
// scores = tail.qk + h.(wf2@qk) + bf2.qk + bk.qc  -- fused into cvt_feat (tail part, fp32)
//   and into the big-GEMM epilogue (h part). scores_k eliminated.
// Big GEMM: 256x256 tile, BK=32, 8 waves, double-buffered LDS, counted vmcnt(4),
//   raw s_barrier (no compiler drain), setprio around MFMA cluster.
// ctx_rt = gather_a(tail) + gather_a(h) @ wf2 + asum*bf2  (32 rows/b survive top-k)

typedef short bf16x8 __attribute__((ext_vector_type(8)));
typedef float f32x4 __attribute__((ext_vector_type(4)));

typedef const __attribute__((address_space(1))) void* gp_t;
typedef __attribute__((address_space(3))) void* lp_t;

__device__ __forceinline__ void ld16(const void* g, void* l) {
  __builtin_amdgcn_global_load_lds((gp_t)g, (lp_t)l, 16, 0, 0);
}

__device__ __forceinline__ unsigned int f2b(float f) {
  unsigned int u = __builtin_bit_cast(unsigned int, f);
  u = (u + 0x7FFFu + ((u >> 16) & 1u)) >> 16;   // RNE
  return u & 0xFFFFu;
}
__device__ __forceinline__ float b2f(unsigned short s) {
  unsigned int u = ((unsigned int)s) << 16;
  return __builtin_bit_cast(float, u);
}
__device__ __forceinline__ float b2f_lo(unsigned int u) { return __builtin_bit_cast(float, u << 16); }
__device__ __forceinline__ float b2f_hi(unsigned int u) { return __builtin_bit_cast(float, u & 0xFFFF0000u); }
__device__ __forceinline__ unsigned int pack2(float lo, float hi) { return f2b(lo) | (f2b(hi) << 16); }

// ---- fp32 -> bf16 convert of concat([tail, rel]) into feat [65536][2048] ----
// FUSED: sc[row] += tail_row(fp32) . qk[b]   (waves 0,1 hold the tail half)
__global__ void cvt_feat_k(const float4* __restrict__ tail, const float4* __restrict__ rel,
                           uint4* __restrict__ feat, const float* __restrict__ qk,
                           float* __restrict__ sc) {
  unsigned t = threadIdx.x;
  unsigned i = blockIdx.x * 256 + t;               // one 8-elem bf16 chunk each
  unsigned row = blockIdx.x, c = t;                // 256 chunks per feat row
  bool isrel = c >= 128u;
  const float4* src = isrel ? rel : tail;
  unsigned s = row * 256u + (c & 127u) * 2u;
  float4 a = src[s], b = src[s + 1];
  uint4 o;
  o.x = pack2(a.x, a.y); o.y = pack2(a.z, a.w);
  o.z = pack2(b.x, b.y); o.w = pack2(b.z, b.w);
  feat[i] = o;
  // tail . qk partial (threads 0..127 = waves 0,1)
  float part = 0.f;
  if (!isrel) {
    const float* qr = qk + (size_t)(row >> 9) * 1024 + c * 8;
    part = a.x * qr[0] + a.y * qr[1] + a.z * qr[2] + a.w * qr[3]
         + b.x * qr[4] + b.y * qr[5] + b.z * qr[6] + b.w * qr[7];
  }
  for (int off = 32; off > 0; off >>= 1) part += __shfl_down(part, off);
  if ((t & 63u) == 0u && !isrel) atomicAdd(sc + row, part);
}

// ---- W [K][N] fp32 -> Wt [N][K] bf16 (tiled transpose) ----
__global__ void transpose_cvt_k(const float* __restrict__ W, unsigned short* __restrict__ Wt,
                                int K, int N) {
  __shared__ float tile[32][33];
  int t = threadIdx.x;
  int tx = t & 31, ty = t >> 5;
  int n0 = blockIdx.x * 32, k0 = blockIdx.y * 32;
  #pragma unroll
  for (int i = 0; i < 32; i += 8)
    tile[ty + i][tx] = W[(size_t)(k0 + ty + i) * N + n0 + tx];
  __syncthreads();
  #pragma unroll
  for (int i = 0; i < 32; i += 8)
    Wt[(size_t)(n0 + ty + i) * K + k0 + tx] = (unsigned short)f2b(tile[tx][ty + i]);
}

// ---- small fp32 GEMM, M=128 fixed, N=1024, K-split over grid.y, atomic accumulate ----
struct SJob { const float* A; const float* W; const float* u; const float* rs;
              const float* A2; float* C; int transB; int pad; };
struct SJobs { SJob j[6]; };

__global__ __launch_bounds__(256) void sgemm_k(SJobs jobs, int K) {
  SJob jb = jobs.j[blockIdx.z];
  __shared__ float At[32 * 132];   // [k][m]
  __shared__ float Wt_[32 * 36];   // [k][n]
  int t = threadIdx.x;
  int n0 = blockIdx.x * 32;
  int kchunk = K / gridDim.y;
  int kbase = blockIdx.y * kchunk;
  int tn = t & 7, tm = t >> 3;
  float acc[4][4] = {};
  for (int kt = 0; kt < kchunk; kt += 32) {
    int k0 = kbase + kt;
    #pragma unroll
    for (int i = 0; i < 16; ++i) {
      int f = i * 256 + t;
      int r = f >> 5, c = f & 31;
      float v = jb.A[(size_t)r * K + k0 + c];
      if (jb.A2) v += jb.A2[(size_t)r * K + k0 + c];
      if (jb.u) v += (jb.rs ? jb.rs[r] : 1.0f) * jb.u[k0 + c];
      At[c * 132 + r] = v;
    }
    #pragma unroll
    for (int i = 0; i < 4; ++i) {
      int f = i * 256 + t;
      if (!jb.transB) { int k = f >> 5, n = f & 31; Wt_[k * 36 + n] = jb.W[(size_t)(k0 + k) * 1024 + n0 + n]; }
      else            { int n = f >> 5, k = f & 31; Wt_[k * 36 + n] = jb.W[(size_t)(n0 + n) * K + k0 + k]; }
    }
    __syncthreads();
    #pragma unroll
    for (int kk = 0; kk < 32; ++kk) {
      float4 av = *(const float4*)&At[kk * 132 + tm * 4];
      float4 wv4 = *(const float4*)&Wt_[kk * 36 + tn * 4];
      float ar[4] = {av.x, av.y, av.z, av.w};
      float wr[4] = {wv4.x, wv4.y, wv4.z, wv4.w};
      #pragma unroll
      for (int r = 0; r < 4; ++r)
        #pragma unroll
        for (int c = 0; c < 4; ++c) acc[r][c] += ar[r] * wr[c];
    }
    __syncthreads();
  }
  #pragma unroll
  for (int r = 0; r < 4; ++r)
    #pragma unroll
    for (int c = 0; c < 4; ++c)
      atomicAdd(jb.C + (size_t)(tm * 4 + r) * 1024 + n0 + tn * 4 + c, acc[r][c]);
}

// ---- elementwise: qc = 0.3125*(0.4*iq+0.6*hq); pout = text*sig(tg)+img*sig(ig) ----
__global__ void ew1_k(const float* __restrict__ riq, const float* __restrict__ rhq,
                      const float* __restrict__ rt, const float* __restrict__ ri,
                      const float* __restrict__ rtg, const float* __restrict__ rig,
                      const float* __restrict__ biq, const float* __restrict__ bhq,
                      const float* __restrict__ blt, const float* __restrict__ bli,
                      const float* __restrict__ bgt, const float* __restrict__ bgi,
                      float* __restrict__ qc, float* __restrict__ pout) {
  int idx = blockIdx.x * 256 + threadIdx.x;
  int n = idx & 1023;
  float iq = riq[idx] + biq[n];
  float hq = rhq[idx] + bhq[n];
  qc[idx] = 0.3125f * (0.4f * iq + 0.6f * hq);
  float tg = 1.0f / (1.0f + expf(-(rtg[idx] + bgt[n])));
  float ig = 1.0f / (1.0f + expf(-(rig[idx] + bgi[n])));
  pout[idx] = (rt[idx] + blt[n]) * tg + (ri[idx] + bli[n]) * ig;
}

// ---- cv[b] = qc[b]·bk + qk[b]·bf2 ----
__global__ void cvec_k(const float* __restrict__ qc, const float* __restrict__ bk,
                       const float* __restrict__ qk, const float* __restrict__ bf2,
                       float* __restrict__ cv) {
  int b = blockIdx.x, l = threadIdx.x;  // 64 threads
  const float4* a = (const float4*)(qc + (size_t)b * 1024);
  const float4* k4 = (const float4*)bk;
  const float4* a2 = (const float4*)(qk + (size_t)b * 1024);
  const float4* k42 = (const float4*)bf2;
  float acc = 0.f;
  #pragma unroll
  for (int i = 0; i < 4; ++i) {
    float4 x = a[l + i * 64], y = k4[l + i * 64];
    acc += x.x * y.x + x.y * y.y + x.z * y.z + x.w * y.w;
    float4 x2 = a2[l + i * 64], y2 = k42[l + i * 64];
    acc += x2.x * y2.x + x2.y * y2.y + x2.z * y2.z + x2.w * y2.w;
  }
  for (int off = 32; off > 0; off >>= 1) acc += __shfl_down(acc, off);
  if (l == 0) cv[b] = acc;
}

// ---- big bf16 MFMA GEMM: h = leaky(A @ Wt^T + bias), bf16 out ----
// 256x256 tile, BK=32, 512 thr (8 waves 2m x 4n, per-wave 128x64), dbuf 64KB LDS,
// counted vmcnt(4) + raw s_barrier, setprio around MFMA.
// FUSED epilogue: sc[m0+row] += h[row,:] . wq2[b, n0:n0+256]
__global__ __launch_bounds__(512, 2) void gemm256_k(
    const unsigned short* __restrict__ A, const unsigned short* __restrict__ Wt,
    const float* __restrict__ bias, const float* __restrict__ wq2,
    unsigned short* __restrict__ C, float* __restrict__ sc, int M, int N, int K) {
  __shared__ __align__(16) unsigned short Sm[32768];  // 64KB: dbuf {A[256][32]|B[256][32]} x2; epilogue Cs[128][256]
  int t = threadIdx.x;
  int l = t & 63, w = t >> 6;

  // XCD swizzle: 4 n-tiles of one m-panel share the same XCD. nwg=1024, 1024%8==0 (bijective).
  int L = blockIdx.x;
  int xcd = L & 7, j = L >> 3;
  int n_t = j & 3;
  int m_t = (j >> 2) * 8 + xcd;
  int m0 = m_t * 256, n0 = n_t * 256;
  int wm = (w >> 2) * 128, wn = (w & 3) * 64;

  // staging: thread t covers, per tensor, rows r0 and r0+128, swizzled 16B slot
  int r0 = t >> 2, slot = t & 3;
  int col8 = slot ^ ((r0 >> 1) & 3);                 // (r0+128) has same (r>>1)&3 parity-class
  const unsigned short* Ag = A + (size_t)(m0 + r0) * K + col8 * 8;
  const unsigned short* Bg = Wt + (size_t)(n0 + r0) * K + col8 * 8;
  size_t rowadv = (size_t)128 * K;
  unsigned short* dA0 = Sm + t * 8;                  // buffer base added at use
  unsigned short* dA1 = Sm + 4096 + t * 8;
  unsigned short* dB0 = Sm + 8192 + t * 8;
  unsigned short* dB1 = Sm + 12288 + t * 8;

  int lm = l & 15, q = l >> 4;
  int aoff[8], boff[4];
  #pragma unroll
  for (int i = 0; i < 8; ++i) {
    int ra = wm + i * 16 + lm;
    aoff[i] = ra * 32 + ((q ^ ((ra >> 1) & 3)) * 8);
  }
  #pragma unroll
  for (int i = 0; i < 4; ++i) {
    int rb = wn + i * 16 + lm;
    boff[i] = rb * 32 + ((q ^ ((rb >> 1) & 3)) * 8);
  }

  f32x4 acc[8][4];
  #pragma unroll
  for (int i = 0; i < 8; ++i)
    #pragma unroll
    for (int jj = 0; jj < 4; ++jj) acc[i][jj] = (f32x4){0.f, 0.f, 0.f, 0.f};

  int NT = K >> 5;

#define STAGE(buf, kt) do {                                     \
    const unsigned short* a_ = Ag + (size_t)(kt) * 32;          \
    const unsigned short* b_ = Bg + (size_t)(kt) * 32;          \
    ld16(a_,          (buf) * 16384 + dA0);                     \
    ld16(a_ + rowadv, (buf) * 16384 + dA1);                     \
    ld16(b_,          (buf) * 16384 + dB0);                     \
    ld16(b_ + rowadv, (buf) * 16384 + dB1);                     \
  } while (0)

#define COMPUTE(cur) do {                                       \
    const unsigned short* base = Sm + (cur) * 16384;            \
    bf16x8 af[8], bfv[4];                                       \
    _Pragma("unroll")                                           \
    for (int i = 0; i < 8; ++i) af[i] = *(const bf16x8*)(base + aoff[i]);        \
    _Pragma("unroll")                                           \
    for (int i = 0; i < 4; ++i) bfv[i] = *(const bf16x8*)(base + 8192 + boff[i]);\
    __builtin_amdgcn_s_setprio(1);                              \
    _Pragma("unroll")                                           \
    for (int mi = 0; mi < 8; ++mi)                              \
      _Pragma("unroll")                                         \
      for (int ni = 0; ni < 4; ++ni)                            \
        acc[mi][ni] = __builtin_amdgcn_mfma_f32_16x16x32_bf16(af[mi], bfv[ni], acc[mi][ni], 0, 0, 0); \
    __builtin_amdgcn_s_setprio(0);                              \
  } while (0)

  STAGE(0, 0);
  for (int kt = 0; kt < NT - 1; ++kt) {
    int cur = kt & 1;
    STAGE(cur ^ 1, kt + 1);
    asm volatile("s_waitcnt vmcnt(4)\n\ts_barrier" ::: "memory");
    COMPUTE(cur);
    asm volatile("s_barrier" ::: "memory");
  }
  asm volatile("s_waitcnt vmcnt(0)\n\ts_barrier" ::: "memory");
  COMPUTE((NT - 1) & 1);
  asm volatile("s_barrier" ::: "memory");

  // ---- epilogue: two half-tiles of 128 rows through 64KB LDS ----
  int lr = q * 4;
  #pragma unroll
  for (int h = 0; h < 2; ++h) {
    if ((w >> 2) == h) {
      #pragma unroll
      for (int mi = 0; mi < 8; ++mi) {
        #pragma unroll
        for (int ni = 0; ni < 4; ++ni) {
          int cn = wn + ni * 16 + lm;
          float bb = bias[n0 + cn];
          #pragma unroll
          for (int r = 0; r < 4; ++r) {
            int row = mi * 16 + lr + r;
            float v = acc[mi][ni][r] + bb;
            v = v > 0.f ? v : 0.01f * v;            // leaky_relu 0.01
            Sm[row * 256 + cn] = (unsigned short)f2b(v);
          }
        }
      }
    }
    __syncthreads();
    // coalesced 16B stores of this half-tile
    #pragma unroll
    for (int p = 0; p < 8; ++p) {
      int idx = p * 512 + t;
      int rr = idx >> 5;
      int c8 = (idx & 31) * 8;
      uint4 cs = *(const uint4*)(Sm + rr * 256 + c8);
      *(uint4*)(C + (size_t)(m0 + h * 128 + rr) * N + n0 + c8) = cs;
    }
    // fused score partial: 4 threads per row, 64 cols each
    {
      int row = t >> 2, quarter = t & 3;
      int b = (m0 + h * 128) >> 9;
      const uint4* cr = (const uint4*)(Sm + row * 256 + quarter * 64);
      const float4* wr = (const float4*)(wq2 + (size_t)b * 1024 + n0 + quarter * 64);
      float part = 0.f;
      #pragma unroll
      for (int jj = 0; jj < 8; ++jj) {
        uint4 cw = cr[jj];
        float4 w0 = wr[jj * 2], w1 = wr[jj * 2 + 1];
        part += b2f_lo(cw.x) * w0.x + b2f_hi(cw.x) * w0.y;
        part += b2f_lo(cw.y) * w0.z + b2f_hi(cw.y) * w0.w;
        part += b2f_lo(cw.z) * w1.x + b2f_hi(cw.z) * w1.y;
        part += b2f_lo(cw.w) * w1.z + b2f_hi(cw.w) * w1.w;
      }
      part += __shfl_xor(part, 1);
      part += __shfl_xor(part, 2);
      if (quarter == 0) atomicAdd(sc + m0 + h * 128 + row, part);
    }
    __syncthreads();
  }
#undef STAGE
#undef COMPUTE
}

// ---- per-b: finalize scores (mask,cv), softmax, top-32 (single-wave select),
//      gather ctxtail = sum a*tail_f32, gh = sum a*h, asum ----
__global__ __launch_bounds__(256) void topk_ctx_k(const float* __restrict__ sc,
                                                  const float* __restrict__ mask,
                                                  const float* __restrict__ cv,
                                                  const float* __restrict__ xtail,
                                                  const unsigned short* __restrict__ h,
                                                  float* __restrict__ ctxtail, float* __restrict__ gh,
                                                  float* __restrict__ asum) {
  int b = blockIdx.x, t = threadIdx.x;
  __shared__ float sv[512];
  __shared__ float red[256];
  __shared__ float topw[32];
  __shared__ int topi[32];
  float cvb = cv[b];
  float r0 = sc[b * 512 + t], r1 = sc[b * 512 + 256 + t];
  float v0 = (mask[b * 512 + t] > 0.01f) ? (r0 + cvb) : -__builtin_inff();
  float v1 = (mask[b * 512 + 256 + t] > 0.01f) ? (r1 + cvb) : -__builtin_inff();
  sv[t] = v0; sv[t + 256] = v1;
  red[t] = fmaxf(v0, v1);
  __syncthreads();
  for (int s = 128; s > 0; s >>= 1) { if (t < s) red[t] = fmaxf(red[t], red[t + s]); __syncthreads(); }
  float mx = red[0];
  __syncthreads();
  float e0 = expf(v0 - mx), e1 = expf(v1 - mx);
  red[t] = e0 + e1;
  __syncthreads();
  for (int s = 128; s > 0; s >>= 1) { if (t < s) red[t] += red[t + s]; __syncthreads(); }
  float inv = 1.0f / red[0];
  __syncthreads();
  sv[t] = e0 * inv; sv[t + 256] = e1 * inv;
  __syncthreads();
  // single-wave top-32 selection (tie -> lower index, matching lax.top_k stability)
  if (t < 64) {
    float v[8];
    int base = t * 8;
    #pragma unroll
    for (int jj = 0; jj < 8; ++jj) v[jj] = sv[base + jj];
    for (int it = 0; it < 32; ++it) {
      float bv = v[0]; int bj = 0;
      #pragma unroll
      for (int jj = 1; jj < 8; ++jj) if (v[jj] > bv) { bv = v[jj]; bj = jj; }
      int bidx = base + bj;
      #pragma unroll
      for (int off = 32; off > 0; off >>= 1) {
        float ov = __shfl_xor(bv, off);
        int oi = __shfl_xor(bidx, off);
        if (ov > bv || (ov == bv && oi < bidx)) { bv = ov; bidx = oi; }
      }
      if (t == (bidx >> 3)) v[bidx & 7] = -1.0f;
      if (t == 0) { topw[it] = bv; topi[it] = bidx; }
    }
  }
  __syncthreads();
  #pragma unroll
  for (int dd = 0; dd < 4; ++dd) {
    int d = t + dd * 256;
    float at = 0.f, ah = 0.f;
    for (int jj = 0; jj < 32; ++jj) {
      size_t ro = (size_t)(b * 512 + topi[jj]) * 1024 + d;
      at += topw[jj] * xtail[ro];
      ah += topw[jj] * b2f(h[ro]);
    }
    ctxtail[(size_t)b * 1024 + d] = at;
    gh[(size_t)b * 1024 + d] = ah;
  }
  if (t == 0) {
    float s = 0.f;
    for (int jj = 0; jj < 32; ++jj) s += topw[jj];
    asum[b] = s;
  }
}

// ---- out = rawL3 + bltr + pout ----
__global__ void ew2_k(const float* __restrict__ r3, const float* __restrict__ bltr,
                      const float* __restrict__ pout, float* __restrict__ out) {
  int idx = blockIdx.x * 256 + threadIdx.x;
  out[idx] = r3[idx] + bltr[idx & 1023] + pout[idx];
}

extern "C" void kernel_launch(void* const* d_in, const int* in_sizes, int n_in,
                              void* d_out, int out_size, void* d_ws, size_t ws_size,
                              hipStream_t stream) {
  const float* x_head = (const float*)d_in[0];
  const float* x_rel  = (const float*)d_in[1];
  const float* x_tail = (const float*)d_in[2];
  const float* x_mask = (const float*)d_in[3];
  const float* x_img  = (const float*)d_in[4];
  const float* wf1 = (const float*)d_in[5];  const float* bf1 = (const float*)d_in[6];
  const float* wf2 = (const float*)d_in[7];  const float* bf2 = (const float*)d_in[8];
  const float* wk  = (const float*)d_in[9];  const float* bk  = (const float*)d_in[10];
  const float* wv  = (const float*)d_in[11]; const float* bv  = (const float*)d_in[12];
  const float* wp  = (const float*)d_in[13]; const float* bp  = (const float*)d_in[14];
  const float* wiq = (const float*)d_in[15]; const float* biq = (const float*)d_in[16];
  const float* whq = (const float*)d_in[17]; const float* bhq = (const float*)d_in[18];
  const float* wlt = (const float*)d_in[19]; const float* blt = (const float*)d_in[20];
  const float* wli = (const float*)d_in[21]; const float* bli = (const float*)d_in[22];
  const float* wltr= (const float*)d_in[23]; const float* bltr= (const float*)d_in[24];
  const float* wgt = (const float*)d_in[25]; const float* bgt = (const float*)d_in[26];
  const float* wgi = (const float*)d_in[27]; const float* bgi = (const float*)d_in[28];
  float* out = (float*)d_out;
  char* ws = (char*)d_ws;

  // workspace layout (bytes)
  unsigned short* feat = (unsigned short*)(ws);                       // 268435456 (stays live)
  unsigned short* hbuf = (unsigned short*)(ws + 268435456ull);        // 134217728
  unsigned short* wf1t = (unsigned short*)(ws + 402653184ull);        // 4194304
  char* z = ws + 406847488ull;                                        // zeroed region
  float* raw_iq = (float*)(z);
  float* raw_hq = (float*)(z + 524288);
  float* raw_t  = (float*)(z + 1048576);
  float* raw_i  = (float*)(z + 1572864);
  float* raw_tg = (float*)(z + 2097152);
  float* raw_ig = (float*)(z + 2621440);
  float* raw_q  = (float*)(z + 3145728);      // qk = qc @ wk^T
  float* wq2    = (float*)(z + 3670016);      // qk @ wf2^T
  float* rawG   = (float*)(z + 4194304);      // gh @ wf2
  float* rawL1  = (float*)(z + 4718592);
  float* rawL2  = (float*)(z + 5242880);
  float* rawL3  = (float*)(z + 5767168);
  float* sc     = (float*)(z + 6291456);      // 262144 bytes, atomically accumulated scores
  float* qc      = (float*)(ws + 413663232ull);
  float* pout    = (float*)(ws + 414187520ull);
  float* cv      = (float*)(ws + 414711808ull);
  float* ctxtail = (float*)(ws + 414715904ull);
  float* gh      = (float*)(ws + 415240192ull);
  float* asum    = (float*)(ws + 415764480ull);

  hipMemsetAsync(z, 0, 6553600, stream);

  // small chain first (inputs only) so qk is ready before cvt_feat's fused tail.qk
  SJobs j6 = {};
  j6.j[0] = SJob{x_img,  wiq, nullptr, nullptr, nullptr, raw_iq, 0, 0};
  j6.j[1] = SJob{x_head, whq, nullptr, nullptr, nullptr, raw_hq, 0, 0};
  j6.j[2] = SJob{x_head, wlt, nullptr, nullptr, nullptr, raw_t,  0, 0};
  j6.j[3] = SJob{x_img,  wli, nullptr, nullptr, nullptr, raw_i,  0, 0};
  j6.j[4] = SJob{x_head, wgt, nullptr, nullptr, nullptr, raw_tg, 0, 0};
  j6.j[5] = SJob{x_img,  wgi, nullptr, nullptr, nullptr, raw_ig, 0, 0};
  sgemm_k<<<dim3(32, 2, 6), 256, 0, stream>>>(j6, 1024);

  ew1_k<<<512, 256, 0, stream>>>(raw_iq, raw_hq, raw_t, raw_i, raw_tg, raw_ig,
                                 biq, bhq, blt, bli, bgt, bgi, qc, pout);

  SJobs jq = {};
  jq.j[0] = SJob{qc, wk, nullptr, nullptr, nullptr, raw_q, 1, 0};   // qk = qc @ wk^T
  sgemm_k<<<dim3(32, 4, 1), 256, 0, stream>>>(jq, 1024);
  jq.j[0] = SJob{raw_q, wf2, nullptr, nullptr, nullptr, wq2, 1, 0}; // wq2 = qk @ wf2^T
  sgemm_k<<<dim3(32, 4, 1), 256, 0, stream>>>(jq, 1024);
  cvec_k<<<128, 64, 0, stream>>>(qc, bk, raw_q, bf2, cv);           // cv = qc·bk + qk·bf2

  cvt_feat_k<<<65536, 256, 0, stream>>>((const float4*)x_tail, (const float4*)x_rel,
                                        (uint4*)feat, raw_q, sc);
  transpose_cvt_k<<<dim3(32, 64), 256, 0, stream>>>(wf1, wf1t, 2048, 1024);

  // h = leaky(feat @ wf1 + bf1); sc += h . wq2
  gemm256_k<<<1024, 512, 0, stream>>>(feat, wf1t, bf1, wq2, hbuf, sc, 65536, 1024, 2048);

  topk_ctx_k<<<128, 256, 0, stream>>>(sc, x_mask, cv, x_tail, hbuf, ctxtail, gh, asum);

  SJobs jl = {};
  jl.j[0] = SJob{gh, wf2, nullptr, nullptr, nullptr, rawG, 0, 0};        // gh @ wf2
  sgemm_k<<<dim3(32, 4, 1), 256, 0, stream>>>(jl, 1024);
  jl.j[0] = SJob{rawG, wv, bf2, asum, ctxtail, rawL1, 0, 0};             // (ctx_rt) @ wv
  sgemm_k<<<dim3(32, 4, 1), 256, 0, stream>>>(jl, 1024);
  jl.j[0] = SJob{rawL1, wp, bv, asum, nullptr, rawL2, 0, 0};             // (+asum*bv) @ wp
  sgemm_k<<<dim3(32, 4, 1), 256, 0, stream>>>(jl, 1024);
  jl.j[0] = SJob{rawL2, wltr, bp, nullptr, nullptr, rawL3, 0, 0};        // (+bp) @ wltr
  sgemm_k<<<dim3(32, 4, 1), 256, 0, stream>>>(jl, 1024);
  ew2_k<<<512, 256, 0, stream>>>(rawL3, bltr, pout, out);
}

// Round 3
// 1361.900 us; speedup vs baseline: 1.2390x; 1.0619x over previous
//
#include <hip/hip_runtime.h>
#include <math.h>

// B=128 S=512 D=1024 P=32 TEMP=0.1 BETA=0.4
// scores = tail.qk + h.(wf2@qk) + bf2.qk + bk.qc  -- fused into cvt_feat (tail part, fp32)
//   and into the big-GEMM epilogue (h part).
// Big GEMM: 256x256 tile, BK=32, 8 waves, FOUR LDS buffers (128KB dynamic), prefetch
//   depth 3, counted vmcnt(12) steady-state (peeled 8/4/0 drain), raw s_barrier,
//   setprio around MFMA cluster.
// ctx_rt = gather_a(tail) + gather_a(h) @ wf2 + asum*bf2  (32 rows/b survive top-k)

typedef short bf16x8 __attribute__((ext_vector_type(8)));
typedef float f32x4 __attribute__((ext_vector_type(4)));

typedef const __attribute__((address_space(1))) void* gp_t;
typedef __attribute__((address_space(3))) void* lp_t;

__device__ __forceinline__ void ld16(const void* g, void* l) {
  __builtin_amdgcn_global_load_lds((gp_t)g, (lp_t)l, 16, 0, 0);
}

__device__ __forceinline__ unsigned int f2b(float f) {
  unsigned int u = __builtin_bit_cast(unsigned int, f);
  u = (u + 0x7FFFu + ((u >> 16) & 1u)) >> 16;   // RNE
  return u & 0xFFFFu;
}
__device__ __forceinline__ float b2f(unsigned short s) {
  unsigned int u = ((unsigned int)s) << 16;
  return __builtin_bit_cast(float, u);
}
__device__ __forceinline__ float b2f_lo(unsigned int u) { return __builtin_bit_cast(float, u << 16); }
__device__ __forceinline__ float b2f_hi(unsigned int u) { return __builtin_bit_cast(float, u & 0xFFFF0000u); }
__device__ __forceinline__ unsigned int pack2(float lo, float hi) { return f2b(lo) | (f2b(hi) << 16); }

// ---- fp32 -> bf16 convert of concat([tail, rel]) into feat [65536][2048] ----
// FUSED: sc[row] += tail_row(fp32) . qk[b]   (waves 0,1 hold the tail half)
__global__ void cvt_feat_k(const float4* __restrict__ tail, const float4* __restrict__ rel,
                           uint4* __restrict__ feat, const float* __restrict__ qk,
                           float* __restrict__ sc) {
  unsigned t = threadIdx.x;
  unsigned i = blockIdx.x * 256 + t;               // one 8-elem bf16 chunk each
  unsigned row = blockIdx.x, c = t;                // 256 chunks per feat row
  bool isrel = c >= 128u;
  const float4* src = isrel ? rel : tail;
  unsigned s = row * 256u + (c & 127u) * 2u;
  float4 a = src[s], b = src[s + 1];
  uint4 o;
  o.x = pack2(a.x, a.y); o.y = pack2(a.z, a.w);
  o.z = pack2(b.x, b.y); o.w = pack2(b.z, b.w);
  feat[i] = o;
  // tail . qk partial (threads 0..127 = waves 0,1)
  float part = 0.f;
  if (!isrel) {
    const float* qr = qk + (size_t)(row >> 9) * 1024 + c * 8;
    part = a.x * qr[0] + a.y * qr[1] + a.z * qr[2] + a.w * qr[3]
         + b.x * qr[4] + b.y * qr[5] + b.z * qr[6] + b.w * qr[7];
  }
  for (int off = 32; off > 0; off >>= 1) part += __shfl_down(part, off);
  if ((t & 63u) == 0u && !isrel) atomicAdd(sc + row, part);
}

// ---- W [K][N] fp32 -> Wt [N][K] bf16 (tiled transpose) ----
__global__ void transpose_cvt_k(const float* __restrict__ W, unsigned short* __restrict__ Wt,
                                int K, int N) {
  __shared__ float tile[32][33];
  int t = threadIdx.x;
  int tx = t & 31, ty = t >> 5;
  int n0 = blockIdx.x * 32, k0 = blockIdx.y * 32;
  #pragma unroll
  for (int i = 0; i < 32; i += 8)
    tile[ty + i][tx] = W[(size_t)(k0 + ty + i) * N + n0 + tx];
  __syncthreads();
  #pragma unroll
  for (int i = 0; i < 32; i += 8)
    Wt[(size_t)(n0 + ty + i) * K + k0 + tx] = (unsigned short)f2b(tile[tx][ty + i]);
}

// ---- small fp32 GEMM, M=128 fixed, N=1024, K-split over grid.y, atomic accumulate ----
struct SJob { const float* A; const float* W; const float* u; const float* rs;
              const float* A2; float* C; int transB; int pad; };
struct SJobs { SJob j[6]; };

__global__ __launch_bounds__(256) void sgemm_k(SJobs jobs, int K) {
  SJob jb = jobs.j[blockIdx.z];
  __shared__ float At[32 * 132];   // [k][m]
  __shared__ float Wt_[32 * 36];   // [k][n]
  int t = threadIdx.x;
  int n0 = blockIdx.x * 32;
  int kchunk = K / gridDim.y;
  int kbase = blockIdx.y * kchunk;
  int tn = t & 7, tm = t >> 3;
  float acc[4][4] = {};
  for (int kt = 0; kt < kchunk; kt += 32) {
    int k0 = kbase + kt;
    #pragma unroll
    for (int i = 0; i < 16; ++i) {
      int f = i * 256 + t;
      int r = f >> 5, c = f & 31;
      float v = jb.A[(size_t)r * K + k0 + c];
      if (jb.A2) v += jb.A2[(size_t)r * K + k0 + c];
      if (jb.u) v += (jb.rs ? jb.rs[r] : 1.0f) * jb.u[k0 + c];
      At[c * 132 + r] = v;
    }
    #pragma unroll
    for (int i = 0; i < 4; ++i) {
      int f = i * 256 + t;
      if (!jb.transB) { int k = f >> 5, n = f & 31; Wt_[k * 36 + n] = jb.W[(size_t)(k0 + k) * 1024 + n0 + n]; }
      else            { int n = f >> 5, k = f & 31; Wt_[k * 36 + n] = jb.W[(size_t)(n0 + n) * K + k0 + k]; }
    }
    __syncthreads();
    #pragma unroll
    for (int kk = 0; kk < 32; ++kk) {
      float4 av = *(const float4*)&At[kk * 132 + tm * 4];
      float4 wv4 = *(const float4*)&Wt_[kk * 36 + tn * 4];
      float ar[4] = {av.x, av.y, av.z, av.w};
      float wr[4] = {wv4.x, wv4.y, wv4.z, wv4.w};
      #pragma unroll
      for (int r = 0; r < 4; ++r)
        #pragma unroll
        for (int c = 0; c < 4; ++c) acc[r][c] += ar[r] * wr[c];
    }
    __syncthreads();
  }
  #pragma unroll
  for (int r = 0; r < 4; ++r)
    #pragma unroll
    for (int c = 0; c < 4; ++c)
      atomicAdd(jb.C + (size_t)(tm * 4 + r) * 1024 + n0 + tn * 4 + c, acc[r][c]);
}

// ---- elementwise: qc = 0.3125*(0.4*iq+0.6*hq); pout = text*sig(tg)+img*sig(ig) ----
__global__ void ew1_k(const float* __restrict__ riq, const float* __restrict__ rhq,
                      const float* __restrict__ rt, const float* __restrict__ ri,
                      const float* __restrict__ rtg, const float* __restrict__ rig,
                      const float* __restrict__ biq, const float* __restrict__ bhq,
                      const float* __restrict__ blt, const float* __restrict__ bli,
                      const float* __restrict__ bgt, const float* __restrict__ bgi,
                      float* __restrict__ qc, float* __restrict__ pout) {
  int idx = blockIdx.x * 256 + threadIdx.x;
  int n = idx & 1023;
  float iq = riq[idx] + biq[n];
  float hq = rhq[idx] + bhq[n];
  qc[idx] = 0.3125f * (0.4f * iq + 0.6f * hq);
  float tg = 1.0f / (1.0f + expf(-(rtg[idx] + bgt[n])));
  float ig = 1.0f / (1.0f + expf(-(rig[idx] + bgi[n])));
  pout[idx] = (rt[idx] + blt[n]) * tg + (ri[idx] + bli[n]) * ig;
}

// ---- cv[b] = qc[b]·bk + qk[b]·bf2 ----
__global__ void cvec_k(const float* __restrict__ qc, const float* __restrict__ bk,
                       const float* __restrict__ qk, const float* __restrict__ bf2,
                       float* __restrict__ cv) {
  int b = blockIdx.x, l = threadIdx.x;  // 64 threads
  const float4* a = (const float4*)(qc + (size_t)b * 1024);
  const float4* k4 = (const float4*)bk;
  const float4* a2 = (const float4*)(qk + (size_t)b * 1024);
  const float4* k42 = (const float4*)bf2;
  float acc = 0.f;
  #pragma unroll
  for (int i = 0; i < 4; ++i) {
    float4 x = a[l + i * 64], y = k4[l + i * 64];
    acc += x.x * y.x + x.y * y.y + x.z * y.z + x.w * y.w;
    float4 x2 = a2[l + i * 64], y2 = k42[l + i * 64];
    acc += x2.x * y2.x + x2.y * y2.y + x2.z * y2.z + x2.w * y2.w;
  }
  for (int off = 32; off > 0; off >>= 1) acc += __shfl_down(acc, off);
  if (l == 0) cv[b] = acc;
}

// ---- big bf16 MFMA GEMM: h = leaky(A @ Wt^T + bias), bf16 out ----
// 256x256 tile, BK=32, 512 thr (8 waves 2m x 4n, per-wave 128x64), 4-buffer ring
// (128KB dynamic LDS), prefetch depth 3, counted vmcnt, raw s_barrier, setprio.
// FUSED epilogue: sc[m0+row] += h[row,:] . wq2[b, n0:n0+256]
__global__ __launch_bounds__(512, 2) void gemm256_k(
    const unsigned short* __restrict__ A, const unsigned short* __restrict__ Wt,
    const float* __restrict__ bias, const float* __restrict__ wq2,
    unsigned short* __restrict__ C, float* __restrict__ sc, int M, int N, int K) {
  extern __shared__ __align__(16) unsigned short Sm[];  // 128KB: 4 x {A[256][32]|B[256][32]}
  int t = threadIdx.x;
  int l = t & 63, w = t >> 6;

  // XCD swizzle: 4 n-tiles of one m-panel share the same XCD. nwg=1024, 1024%8==0 (bijective).
  int L = blockIdx.x;
  int xcd = L & 7, j = L >> 3;
  int n_t = j & 3;
  int m_t = (j >> 2) * 8 + xcd;
  int m0 = m_t * 256, n0 = n_t * 256;
  int wm = (w >> 2) * 128, wn = (w & 3) * 64;

  // staging: thread t covers, per tensor, rows r0 and r0+128, swizzled 16B slot
  int r0 = t >> 2, slot = t & 3;
  int col8 = slot ^ ((r0 >> 1) & 3);
  const unsigned short* Ag = A + (size_t)(m0 + r0) * K + col8 * 8;
  const unsigned short* Bg = Wt + (size_t)(n0 + r0) * K + col8 * 8;
  size_t rowadv = (size_t)128 * K;
  unsigned short* dA0 = Sm + t * 8;                  // buffer base added at use
  unsigned short* dA1 = Sm + 4096 + t * 8;
  unsigned short* dB0 = Sm + 8192 + t * 8;
  unsigned short* dB1 = Sm + 12288 + t * 8;

  int lm = l & 15, q = l >> 4;
  int aoff[8], boff[4];
  #pragma unroll
  for (int i = 0; i < 8; ++i) {
    int ra = wm + i * 16 + lm;
    aoff[i] = ra * 32 + ((q ^ ((ra >> 1) & 3)) * 8);
  }
  #pragma unroll
  for (int i = 0; i < 4; ++i) {
    int rb = wn + i * 16 + lm;
    boff[i] = rb * 32 + ((q ^ ((rb >> 1) & 3)) * 8);
  }

  f32x4 acc[8][4];
  #pragma unroll
  for (int i = 0; i < 8; ++i)
    #pragma unroll
    for (int jj = 0; jj < 4; ++jj) acc[i][jj] = (f32x4){0.f, 0.f, 0.f, 0.f};

  int NT = K >> 5;   // 64

#define STAGE(buf, kt) do {                                     \
    const unsigned short* a_ = Ag + (size_t)(kt) * 32;          \
    const unsigned short* b_ = Bg + (size_t)(kt) * 32;          \
    ld16(a_,          (buf) * 16384 + dA0);                     \
    ld16(a_ + rowadv, (buf) * 16384 + dA1);                     \
    ld16(b_,          (buf) * 16384 + dB0);                     \
    ld16(b_ + rowadv, (buf) * 16384 + dB1);                     \
  } while (0)

#define COMPUTE(cur) do {                                       \
    const unsigned short* base = Sm + (cur) * 16384;            \
    bf16x8 af[8], bfv[4];                                       \
    _Pragma("unroll")                                           \
    for (int i = 0; i < 8; ++i) af[i] = *(const bf16x8*)(base + aoff[i]);        \
    _Pragma("unroll")                                           \
    for (int i = 0; i < 4; ++i) bfv[i] = *(const bf16x8*)(base + 8192 + boff[i]);\
    __builtin_amdgcn_s_setprio(1);                              \
    _Pragma("unroll")                                           \
    for (int mi = 0; mi < 8; ++mi)                              \
      _Pragma("unroll")                                         \
      for (int ni = 0; ni < 4; ++ni)                            \
        acc[mi][ni] = __builtin_amdgcn_mfma_f32_16x16x32_bf16(af[mi], bfv[ni], acc[mi][ni], 0, 0, 0); \
    __builtin_amdgcn_s_setprio(0);                              \
  } while (0)

  // depth-3 software pipeline over a 4-buffer ring.
  STAGE(0, 0);
  STAGE(1, 1);
  STAGE(2, 2);
  for (int kt = 0; kt + 3 < NT; ++kt) {
    STAGE((kt + 3) & 3, kt + 3);
    // outstanding after stage: 12 loads (kt+1,kt+2,kt+3); wait drains buffer kt's loads
    asm volatile("s_waitcnt vmcnt(12)\n\ts_barrier" ::: "memory");
    COMPUTE(kt & 3);
    asm volatile("s_barrier" ::: "memory");
  }
  // drain: kt = NT-3, NT-2, NT-1
  asm volatile("s_waitcnt vmcnt(8)\n\ts_barrier" ::: "memory");
  COMPUTE((NT - 3) & 3);
  asm volatile("s_barrier" ::: "memory");
  asm volatile("s_waitcnt vmcnt(4)\n\ts_barrier" ::: "memory");
  COMPUTE((NT - 2) & 3);
  asm volatile("s_barrier" ::: "memory");
  asm volatile("s_waitcnt vmcnt(0)\n\ts_barrier" ::: "memory");
  COMPUTE((NT - 1) & 3);
  asm volatile("s_barrier" ::: "memory");

  // ---- epilogue: two half-tiles of 128 rows through LDS (reuses ring space) ----
  int lr = q * 4;
  #pragma unroll
  for (int h = 0; h < 2; ++h) {
    if ((w >> 2) == h) {
      #pragma unroll
      for (int mi = 0; mi < 8; ++mi) {
        #pragma unroll
        for (int ni = 0; ni < 4; ++ni) {
          int cn = wn + ni * 16 + lm;
          float bb = bias[n0 + cn];
          #pragma unroll
          for (int r = 0; r < 4; ++r) {
            int row = mi * 16 + lr + r;
            float v = acc[mi][ni][r] + bb;
            v = v > 0.f ? v : 0.01f * v;            // leaky_relu 0.01
            Sm[row * 256 + cn] = (unsigned short)f2b(v);
          }
        }
      }
    }
    __syncthreads();
    // coalesced 16B stores of this half-tile
    #pragma unroll
    for (int p = 0; p < 8; ++p) {
      int idx = p * 512 + t;
      int rr = idx >> 5;
      int c8 = (idx & 31) * 8;
      uint4 cs = *(const uint4*)(Sm + rr * 256 + c8);
      *(uint4*)(C + (size_t)(m0 + h * 128 + rr) * N + n0 + c8) = cs;
    }
    // fused score partial: 4 threads per row, 64 cols each
    {
      int row = t >> 2, quarter = t & 3;
      int b = (m0 + h * 128) >> 9;
      const uint4* cr = (const uint4*)(Sm + row * 256 + quarter * 64);
      const float4* wr = (const float4*)(wq2 + (size_t)b * 1024 + n0 + quarter * 64);
      float part = 0.f;
      #pragma unroll
      for (int jj = 0; jj < 8; ++jj) {
        uint4 cw = cr[jj];
        float4 w0 = wr[jj * 2], w1 = wr[jj * 2 + 1];
        part += b2f_lo(cw.x) * w0.x + b2f_hi(cw.x) * w0.y;
        part += b2f_lo(cw.y) * w0.z + b2f_hi(cw.y) * w0.w;
        part += b2f_lo(cw.z) * w1.x + b2f_hi(cw.z) * w1.y;
        part += b2f_lo(cw.w) * w1.z + b2f_hi(cw.w) * w1.w;
      }
      part += __shfl_xor(part, 1);
      part += __shfl_xor(part, 2);
      if (quarter == 0) atomicAdd(sc + m0 + h * 128 + row, part);
    }
    __syncthreads();
  }
#undef STAGE
#undef COMPUTE
}

// ---- per-b: finalize scores (mask,cv), softmax, top-32 (single-wave select),
//      gather ctxtail = sum a*tail_f32, gh = sum a*h, asum ----
__global__ __launch_bounds__(256) void topk_ctx_k(const float* __restrict__ sc,
                                                  const float* __restrict__ mask,
                                                  const float* __restrict__ cv,
                                                  const float* __restrict__ xtail,
                                                  const unsigned short* __restrict__ h,
                                                  float* __restrict__ ctxtail, float* __restrict__ gh,
                                                  float* __restrict__ asum) {
  int b = blockIdx.x, t = threadIdx.x;
  __shared__ float sv[512];
  __shared__ float red[256];
  __shared__ float topw[32];
  __shared__ int topi[32];
  float cvb = cv[b];
  float r0 = sc[b * 512 + t], r1 = sc[b * 512 + 256 + t];
  float v0 = (mask[b * 512 + t] > 0.01f) ? (r0 + cvb) : -__builtin_inff();
  float v1 = (mask[b * 512 + 256 + t] > 0.01f) ? (r1 + cvb) : -__builtin_inff();
  sv[t] = v0; sv[t + 256] = v1;
  red[t] = fmaxf(v0, v1);
  __syncthreads();
  for (int s = 128; s > 0; s >>= 1) { if (t < s) red[t] = fmaxf(red[t], red[t + s]); __syncthreads(); }
  float mx = red[0];
  __syncthreads();
  float e0 = expf(v0 - mx), e1 = expf(v1 - mx);
  red[t] = e0 + e1;
  __syncthreads();
  for (int s = 128; s > 0; s >>= 1) { if (t < s) red[t] += red[t + s]; __syncthreads(); }
  float inv = 1.0f / red[0];
  __syncthreads();
  sv[t] = e0 * inv; sv[t + 256] = e1 * inv;
  __syncthreads();
  // single-wave top-32 selection (tie -> lower index, matching lax.top_k stability)
  if (t < 64) {
    float v[8];
    int base = t * 8;
    #pragma unroll
    for (int jj = 0; jj < 8; ++jj) v[jj] = sv[base + jj];
    for (int it = 0; it < 32; ++it) {
      float bv = v[0]; int bj = 0;
      #pragma unroll
      for (int jj = 1; jj < 8; ++jj) if (v[jj] > bv) { bv = v[jj]; bj = jj; }
      int bidx = base + bj;
      #pragma unroll
      for (int off = 32; off > 0; off >>= 1) {
        float ov = __shfl_xor(bv, off);
        int oi = __shfl_xor(bidx, off);
        if (ov > bv || (ov == bv && oi < bidx)) { bv = ov; bidx = oi; }
      }
      if (t == (bidx >> 3)) v[bidx & 7] = -1.0f;
      if (t == 0) { topw[it] = bv; topi[it] = bidx; }
    }
  }
  __syncthreads();
  #pragma unroll
  for (int dd = 0; dd < 4; ++dd) {
    int d = t + dd * 256;
    float at = 0.f, ah = 0.f;
    for (int jj = 0; jj < 32; ++jj) {
      size_t ro = (size_t)(b * 512 + topi[jj]) * 1024 + d;
      at += topw[jj] * xtail[ro];
      ah += topw[jj] * b2f(h[ro]);
    }
    ctxtail[(size_t)b * 1024 + d] = at;
    gh[(size_t)b * 1024 + d] = ah;
  }
  if (t == 0) {
    float s = 0.f;
    for (int jj = 0; jj < 32; ++jj) s += topw[jj];
    asum[b] = s;
  }
}

// ---- out = rawL3 + bltr + pout ----
__global__ void ew2_k(const float* __restrict__ r3, const float* __restrict__ bltr,
                      const float* __restrict__ pout, float* __restrict__ out) {
  int idx = blockIdx.x * 256 + threadIdx.x;
  out[idx] = r3[idx] + bltr[idx & 1023] + pout[idx];
}

extern "C" void kernel_launch(void* const* d_in, const int* in_sizes, int n_in,
                              void* d_out, int out_size, void* d_ws, size_t ws_size,
                              hipStream_t stream) {
  const float* x_head = (const float*)d_in[0];
  const float* x_rel  = (const float*)d_in[1];
  const float* x_tail = (const float*)d_in[2];
  const float* x_mask = (const float*)d_in[3];
  const float* x_img  = (const float*)d_in[4];
  const float* wf1 = (const float*)d_in[5];  const float* bf1 = (const float*)d_in[6];
  const float* wf2 = (const float*)d_in[7];  const float* bf2 = (const float*)d_in[8];
  const float* wk  = (const float*)d_in[9];  const float* bk  = (const float*)d_in[10];
  const float* wv  = (const float*)d_in[11]; const float* bv  = (const float*)d_in[12];
  const float* wp  = (const float*)d_in[13]; const float* bp  = (const float*)d_in[14];
  const float* wiq = (const float*)d_in[15]; const float* biq = (const float*)d_in[16];
  const float* whq = (const float*)d_in[17]; const float* bhq = (const float*)d_in[18];
  const float* wlt = (const float*)d_in[19]; const float* blt = (const float*)d_in[20];
  const float* wli = (const float*)d_in[21]; const float* bli = (const float*)d_in[22];
  const float* wltr= (const float*)d_in[23]; const float* bltr= (const float*)d_in[24];
  const float* wgt = (const float*)d_in[25]; const float* bgt = (const float*)d_in[26];
  const float* wgi = (const float*)d_in[27]; const float* bgi = (const float*)d_in[28];
  float* out = (float*)d_out;
  char* ws = (char*)d_ws;

  // workspace layout (bytes)
  unsigned short* feat = (unsigned short*)(ws);                       // 268435456 (stays live)
  unsigned short* hbuf = (unsigned short*)(ws + 268435456ull);        // 134217728
  unsigned short* wf1t = (unsigned short*)(ws + 402653184ull);        // 4194304
  char* z = ws + 406847488ull;                                        // zeroed region
  float* raw_iq = (float*)(z);
  float* raw_hq = (float*)(z + 524288);
  float* raw_t  = (float*)(z + 1048576);
  float* raw_i  = (float*)(z + 1572864);
  float* raw_tg = (float*)(z + 2097152);
  float* raw_ig = (float*)(z + 2621440);
  float* raw_q  = (float*)(z + 3145728);      // qk = qc @ wk^T
  float* wq2    = (float*)(z + 3670016);      // qk @ wf2^T
  float* rawG   = (float*)(z + 4194304);      // gh @ wf2
  float* rawL1  = (float*)(z + 4718592);
  float* rawL2  = (float*)(z + 5242880);
  float* rawL3  = (float*)(z + 5767168);
  float* sc     = (float*)(z + 6291456);      // 262144 bytes, atomically accumulated scores
  float* qc      = (float*)(ws + 413663232ull);
  float* pout    = (float*)(ws + 414187520ull);
  float* cv      = (float*)(ws + 414711808ull);
  float* ctxtail = (float*)(ws + 414715904ull);
  float* gh      = (float*)(ws + 415240192ull);
  float* asum    = (float*)(ws + 415764480ull);

  // allow 128KB dynamic LDS for the big GEMM (host-side attr, graph-capture safe)
  hipFuncSetAttribute((const void*)gemm256_k,
                      hipFuncAttributeMaxDynamicSharedMemorySize, 131072);

  hipMemsetAsync(z, 0, 6553600, stream);

  // small chain first (inputs only) so qk is ready before cvt_feat's fused tail.qk
  SJobs j6 = {};
  j6.j[0] = SJob{x_img,  wiq, nullptr, nullptr, nullptr, raw_iq, 0, 0};
  j6.j[1] = SJob{x_head, whq, nullptr, nullptr, nullptr, raw_hq, 0, 0};
  j6.j[2] = SJob{x_head, wlt, nullptr, nullptr, nullptr, raw_t,  0, 0};
  j6.j[3] = SJob{x_img,  wli, nullptr, nullptr, nullptr, raw_i,  0, 0};
  j6.j[4] = SJob{x_head, wgt, nullptr, nullptr, nullptr, raw_tg, 0, 0};
  j6.j[5] = SJob{x_img,  wgi, nullptr, nullptr, nullptr, raw_ig, 0, 0};
  sgemm_k<<<dim3(32, 4, 6), 256, 0, stream>>>(j6, 1024);

  ew1_k<<<512, 256, 0, stream>>>(raw_iq, raw_hq, raw_t, raw_i, raw_tg, raw_ig,
                                 biq, bhq, blt, bli, bgt, bgi, qc, pout);

  SJobs jq = {};
  jq.j[0] = SJob{qc, wk, nullptr, nullptr, nullptr, raw_q, 1, 0};   // qk = qc @ wk^T
  sgemm_k<<<dim3(32, 8, 1), 256, 0, stream>>>(jq, 1024);
  jq.j[0] = SJob{raw_q, wf2, nullptr, nullptr, nullptr, wq2, 1, 0}; // wq2 = qk @ wf2^T
  sgemm_k<<<dim3(32, 8, 1), 256, 0, stream>>>(jq, 1024);
  cvec_k<<<128, 64, 0, stream>>>(qc, bk, raw_q, bf2, cv);           // cv = qc·bk + qk·bf2

  cvt_feat_k<<<65536, 256, 0, stream>>>((const float4*)x_tail, (const float4*)x_rel,
                                        (uint4*)feat, raw_q, sc);
  transpose_cvt_k<<<dim3(32, 64), 256, 0, stream>>>(wf1, wf1t, 2048, 1024);

  // h = leaky(feat @ wf1 + bf1); sc += h . wq2
  gemm256_k<<<1024, 512, 131072, stream>>>(feat, wf1t, bf1, wq2, hbuf, sc, 65536, 1024, 2048);

  topk_ctx_k<<<128, 256, 0, stream>>>(sc, x_mask, cv, x_tail, hbuf, ctxtail, gh, asum);

  SJobs jl = {};
  jl.j[0] = SJob{gh, wf2, nullptr, nullptr, nullptr, rawG, 0, 0};        // gh @ wf2
  sgemm_k<<<dim3(32, 8, 1), 256, 0, stream>>>(jl, 1024);
  jl.j[0] = SJob{rawG, wv, bf2, asum, ctxtail, rawL1, 0, 0};             // (ctx_rt) @ wv
  sgemm_k<<<dim3(32, 8, 1), 256, 0, stream>>>(jl, 1024);
  jl.j[0] = SJob{rawL1, wp, bv, asum, nullptr, rawL2, 0, 0};             // (+asum*bv) @ wp
  sgemm_k<<<dim3(32, 8, 1), 256, 0, stream>>>(jl, 1024);
  jl.j[0] = SJob{rawL2, wltr, bp, nullptr, nullptr, rawL3, 0, 0};        // (+bp) @ wltr
  sgemm_k<<<dim3(32, 8, 1), 256, 0, stream>>>(jl, 1024);
  ew2_k<<<512, 256, 0, stream>>>(rawL3, bltr, pout, out);
}

// Round 4
// 1348.814 us; speedup vs baseline: 1.2511x; 1.0097x over previous
//
#include <hip/hip_runtime.h>
#include <math.h>

// B=128 S=512 D=1024 P=32 TEMP=0.1 BETA=0.4
// scores = tail.qk + h.(wf2@qk) + bf2.qk + bk.qc  -- fused into cvt_feat (tail part, fp32)
//   and into the big-GEMM epilogue (h part).
// Big GEMM: 256x256 tile, BK=64, 8 waves, 2-buffer dbuf (128KB dynamic LDS),
//   4 phases per K-tile (8 per 2 K-tiles, m201-style): per phase
//   {ds_read subtile | 2x global_load_lds | barrier | lgkmcnt(0) | 16 MFMA | barrier},
//   counted vmcnt(4) at P2/P4 end only (never 0 in-loop), setprio around MFMA.
// ctx_rt = gather_a(tail) + gather_a(h) @ wf2 + asum*bf2  (32 rows/b survive top-k)

typedef short bf16x8 __attribute__((ext_vector_type(8)));
typedef float f32x4 __attribute__((ext_vector_type(4)));

typedef const __attribute__((address_space(1))) void* gp_t;
typedef __attribute__((address_space(3))) void* lp_t;

__device__ __forceinline__ void ld16(const void* g, void* l) {
  __builtin_amdgcn_global_load_lds((gp_t)g, (lp_t)l, 16, 0, 0);
}

__device__ __forceinline__ unsigned int f2b(float f) {
  unsigned int u = __builtin_bit_cast(unsigned int, f);
  u = (u + 0x7FFFu + ((u >> 16) & 1u)) >> 16;   // RNE
  return u & 0xFFFFu;
}
__device__ __forceinline__ float b2f(unsigned short s) {
  unsigned int u = ((unsigned int)s) << 16;
  return __builtin_bit_cast(float, u);
}
__device__ __forceinline__ float b2f_lo(unsigned int u) { return __builtin_bit_cast(float, u << 16); }
__device__ __forceinline__ float b2f_hi(unsigned int u) { return __builtin_bit_cast(float, u & 0xFFFF0000u); }
__device__ __forceinline__ unsigned int pack2(float lo, float hi) { return f2b(lo) | (f2b(hi) << 16); }

// ---- fp32 -> bf16 convert of concat([tail, rel]) into feat [65536][2048] ----
// FUSED: sc[row] += tail_row(fp32) . qk[b]   (waves 0,1 hold the tail half)
__global__ void cvt_feat_k(const float4* __restrict__ tail, const float4* __restrict__ rel,
                           uint4* __restrict__ feat, const float* __restrict__ qk,
                           float* __restrict__ sc) {
  unsigned t = threadIdx.x;
  unsigned i = blockIdx.x * 256 + t;               // one 8-elem bf16 chunk each
  unsigned row = blockIdx.x, c = t;                // 256 chunks per feat row
  bool isrel = c >= 128u;
  const float4* src = isrel ? rel : tail;
  unsigned s = row * 256u + (c & 127u) * 2u;
  float4 a = src[s], b = src[s + 1];
  uint4 o;
  o.x = pack2(a.x, a.y); o.y = pack2(a.z, a.w);
  o.z = pack2(b.x, b.y); o.w = pack2(b.z, b.w);
  feat[i] = o;
  // tail . qk partial (threads 0..127 = waves 0,1)
  float part = 0.f;
  if (!isrel) {
    const float* qr = qk + (size_t)(row >> 9) * 1024 + c * 8;
    part = a.x * qr[0] + a.y * qr[1] + a.z * qr[2] + a.w * qr[3]
         + b.x * qr[4] + b.y * qr[5] + b.z * qr[6] + b.w * qr[7];
  }
  for (int off = 32; off > 0; off >>= 1) part += __shfl_down(part, off);
  if ((t & 63u) == 0u && !isrel) atomicAdd(sc + row, part);
}

// ---- W [K][N] fp32 -> Wt [N][K] bf16 (tiled transpose) ----
__global__ void transpose_cvt_k(const float* __restrict__ W, unsigned short* __restrict__ Wt,
                                int K, int N) {
  __shared__ float tile[32][33];
  int t = threadIdx.x;
  int tx = t & 31, ty = t >> 5;
  int n0 = blockIdx.x * 32, k0 = blockIdx.y * 32;
  #pragma unroll
  for (int i = 0; i < 32; i += 8)
    tile[ty + i][tx] = W[(size_t)(k0 + ty + i) * N + n0 + tx];
  __syncthreads();
  #pragma unroll
  for (int i = 0; i < 32; i += 8)
    Wt[(size_t)(n0 + ty + i) * K + k0 + tx] = (unsigned short)f2b(tile[tx][ty + i]);
}

// ---- small fp32 GEMM, M=128 fixed, N=1024, K-split over grid.y, atomic accumulate ----
struct SJob { const float* A; const float* W; const float* u; const float* rs;
              const float* A2; float* C; int transB; int pad; };
struct SJobs { SJob j[6]; };

__global__ __launch_bounds__(256) void sgemm_k(SJobs jobs, int K) {
  SJob jb = jobs.j[blockIdx.z];
  __shared__ float At[32 * 132];   // [k][m]
  __shared__ float Wt_[32 * 36];   // [k][n]
  int t = threadIdx.x;
  int n0 = blockIdx.x * 32;
  int kchunk = K / gridDim.y;
  int kbase = blockIdx.y * kchunk;
  int tn = t & 7, tm = t >> 3;
  float acc[4][4] = {};
  for (int kt = 0; kt < kchunk; kt += 32) {
    int k0 = kbase + kt;
    #pragma unroll
    for (int i = 0; i < 16; ++i) {
      int f = i * 256 + t;
      int r = f >> 5, c = f & 31;
      float v = jb.A[(size_t)r * K + k0 + c];
      if (jb.A2) v += jb.A2[(size_t)r * K + k0 + c];
      if (jb.u) v += (jb.rs ? jb.rs[r] : 1.0f) * jb.u[k0 + c];
      At[c * 132 + r] = v;
    }
    #pragma unroll
    for (int i = 0; i < 4; ++i) {
      int f = i * 256 + t;
      if (!jb.transB) { int k = f >> 5, n = f & 31; Wt_[k * 36 + n] = jb.W[(size_t)(k0 + k) * 1024 + n0 + n]; }
      else            { int n = f >> 5, k = f & 31; Wt_[k * 36 + n] = jb.W[(size_t)(n0 + n) * K + k0 + k]; }
    }
    __syncthreads();
    #pragma unroll
    for (int kk = 0; kk < 32; ++kk) {
      float4 av = *(const float4*)&At[kk * 132 + tm * 4];
      float4 wv4 = *(const float4*)&Wt_[kk * 36 + tn * 4];
      float ar[4] = {av.x, av.y, av.z, av.w};
      float wr[4] = {wv4.x, wv4.y, wv4.z, wv4.w};
      #pragma unroll
      for (int r = 0; r < 4; ++r)
        #pragma unroll
        for (int c = 0; c < 4; ++c) acc[r][c] += ar[r] * wr[c];
    }
    __syncthreads();
  }
  #pragma unroll
  for (int r = 0; r < 4; ++r)
    #pragma unroll
    for (int c = 0; c < 4; ++c)
      atomicAdd(jb.C + (size_t)(tm * 4 + r) * 1024 + n0 + tn * 4 + c, acc[r][c]);
}

// ---- elementwise: qc = 0.3125*(0.4*iq+0.6*hq); pout = text*sig(tg)+img*sig(ig) ----
__global__ void ew1_k(const float* __restrict__ riq, const float* __restrict__ rhq,
                      const float* __restrict__ rt, const float* __restrict__ ri,
                      const float* __restrict__ rtg, const float* __restrict__ rig,
                      const float* __restrict__ biq, const float* __restrict__ bhq,
                      const float* __restrict__ blt, const float* __restrict__ bli,
                      const float* __restrict__ bgt, const float* __restrict__ bgi,
                      float* __restrict__ qc, float* __restrict__ pout) {
  int idx = blockIdx.x * 256 + threadIdx.x;
  int n = idx & 1023;
  float iq = riq[idx] + biq[n];
  float hq = rhq[idx] + bhq[n];
  qc[idx] = 0.3125f * (0.4f * iq + 0.6f * hq);
  float tg = 1.0f / (1.0f + expf(-(rtg[idx] + bgt[n])));
  float ig = 1.0f / (1.0f + expf(-(rig[idx] + bgi[n])));
  pout[idx] = (rt[idx] + blt[n]) * tg + (ri[idx] + bli[n]) * ig;
}

// ---- cv[b] = qc[b]·bk + qk[b]·bf2 ----
__global__ void cvec_k(const float* __restrict__ qc, const float* __restrict__ bk,
                       const float* __restrict__ qk, const float* __restrict__ bf2,
                       float* __restrict__ cv) {
  int b = blockIdx.x, l = threadIdx.x;  // 64 threads
  const float4* a = (const float4*)(qc + (size_t)b * 1024);
  const float4* k4 = (const float4*)bk;
  const float4* a2 = (const float4*)(qk + (size_t)b * 1024);
  const float4* k42 = (const float4*)bf2;
  float acc = 0.f;
  #pragma unroll
  for (int i = 0; i < 4; ++i) {
    float4 x = a[l + i * 64], y = k4[l + i * 64];
    acc += x.x * y.x + x.y * y.y + x.z * y.z + x.w * y.w;
    float4 x2 = a2[l + i * 64], y2 = k42[l + i * 64];
    acc += x2.x * y2.x + x2.y * y2.y + x2.z * y2.z + x2.w * y2.w;
  }
  for (int off = 32; off > 0; off >>= 1) acc += __shfl_down(acc, off);
  if (l == 0) cv[b] = acc;
}

// ---- big bf16 MFMA GEMM: h = leaky(A @ Wt^T + bias), bf16 out ----
// 256x256 tile, BK=64, 512 thr (8 waves 2m x 4n, per-wave 128x64), 2-buf dbuf,
// 4 phases/K-tile, counted vmcnt(4), raw s_barrier, setprio.
// LDS per buf (shorts): [A-h0: 0][B-h0: 8192][A-h1: 16384][B-h1: 24576]; buf stride 32768.
// half = 32 k-cols; row stride 32 shorts; 16B slot swizzle: slot' = slot ^ ((row>>1)&3).
// FUSED epilogue: sc[m0+row] += h[row,:] . wq2[b, n0:n0+256]
__global__ __launch_bounds__(512, 2) void gemm256_k(
    const unsigned short* __restrict__ A, const unsigned short* __restrict__ Wt,
    const float* __restrict__ bias, const float* __restrict__ wq2,
    unsigned short* __restrict__ C, float* __restrict__ sc, int M, int N, int K) {
  extern __shared__ __align__(16) unsigned short Sm[];  // 128KB
  int t = threadIdx.x;
  int l = t & 63, w = t >> 6;

  // XCD swizzle: 4 n-tiles of one m-panel share the same XCD. nwg=1024, 1024%8==0 (bijective).
  int L = blockIdx.x;
  int xcd = L & 7, j = L >> 3;
  int n_t = j & 3;
  int m_t = (j >> 2) * 8 + xcd;
  int m0 = m_t * 256, n0 = n_t * 256;
  int wm = (w >> 2) * 128, wn = (w & 3) * 64;

  // staging per-thread constants: round = 128 rows x 32 k = 8KB, one ld16/thread.
  // thread t -> row-in-block rw = t>>2, slot = t&3; global col-block = slot ^ ((rw>>1)&3)
  // (row+128 has same (row>>1)&3 bits; LDS dest linear = base + t*16)
  int rw = t >> 2;
  int csw = (t & 3) ^ ((rw >> 1) & 3);
  const unsigned short* A0g = A + (size_t)(m0 + rw) * K + csw * 8;
  const unsigned short* A1g = A + (size_t)(m0 + 128 + rw) * K + csw * 8;
  const unsigned short* B0g = Wt + (size_t)(n0 + rw) * K + csw * 8;
  const unsigned short* B1g = Wt + (size_t)(n0 + 128 + rw) * K + csw * 8;
  unsigned short* dst = Sm + t * 8;   // + buf*32768 + round*4096

  int lm = l & 15, q = l >> 4;
  int slotx = (q ^ ((lm >> 1) & 3)) * 8;     // swizzled 16B slot within 32-col half (shorts)
  int aoff[8], boff[4];
  #pragma unroll
  for (int i = 0; i < 8; ++i) aoff[i] = (wm + i * 16 + lm) * 32 + slotx;
  #pragma unroll
  for (int i = 0; i < 4; ++i) boff[i] = 8192 + (wn + i * 16 + lm) * 32 + slotx;
  // frag read addr = Sm + buf*32768 + ks*16384 + aoff/boff

  f32x4 acc[8][4];
  #pragma unroll
  for (int i = 0; i < 8; ++i)
    #pragma unroll
    for (int jj = 0; jj < 4; ++jj) acc[i][jj] = (f32x4){0.f, 0.f, 0.f, 0.f};

  int NT = K >> 6;   // 32 K-tiles of 64

#define MFMA16(mbase, ks)                                                 \
    __builtin_amdgcn_s_setprio(1);                                        \
    _Pragma("unroll")                                                     \
    for (int mi = 0; mi < 4; ++mi)                                        \
      _Pragma("unroll")                                                   \
      for (int ni = 0; ni < 4; ++ni)                                      \
        acc[(mbase) + mi][ni] =                                           \
          __builtin_amdgcn_mfma_f32_16x16x32_bf16(aF[mi], bF[ni], acc[(mbase) + mi][ni], 0, 0, 0); \
    __builtin_amdgcn_s_setprio(0);

  // prologue: stage tile 0 (8 rounds) into buf0; allow tile0-h1 (4) to stay in flight
  ld16(A0g, dst);          ld16(A1g, dst + 4096);
  ld16(B0g, dst + 8192);   ld16(B1g, dst + 12288);
  ld16(A0g + 32, dst + 16384); ld16(A1g + 32, dst + 20480);
  ld16(B0g + 32, dst + 24576); ld16(B1g + 32, dst + 28672);
  asm volatile("s_waitcnt vmcnt(4)\n\ts_barrier" ::: "memory");

  for (int kt = 0; kt < NT; ++kt) {
    const unsigned short* base = Sm + (kt & 1) * 32768;
    unsigned short* nd = dst + ((kt & 1) ^ 1) * 32768;
    size_t ksrc = (size_t)((kt + 1 < NT) ? (kt + 1) : kt) * 64;
    bf16x8 aF[4], bF[4];

    // ---- P1: ds_read B(ks0), A m0-3(ks0); stage A-h0 of next tile ----
    #pragma unroll
    for (int i = 0; i < 4; ++i) bF[i] = *(const bf16x8*)(base + boff[i]);
    #pragma unroll
    for (int i = 0; i < 4; ++i) aF[i] = *(const bf16x8*)(base + aoff[i]);
    ld16(A0g + ksrc, nd);
    ld16(A1g + ksrc, nd + 4096);
    __builtin_amdgcn_s_barrier();
    asm volatile("s_waitcnt lgkmcnt(0)" ::: "memory");
    __builtin_amdgcn_sched_barrier(0);
    MFMA16(0, 0)
    __builtin_amdgcn_s_barrier();

    // ---- P2: ds_read A m4-7(ks0); stage B-h0; MFMA (bF held); vmcnt(4) ----
    #pragma unroll
    for (int i = 0; i < 4; ++i) aF[i] = *(const bf16x8*)(base + aoff[4 + i]);
    ld16(B0g + ksrc, nd + 8192);
    ld16(B1g + ksrc, nd + 12288);
    __builtin_amdgcn_s_barrier();
    asm volatile("s_waitcnt lgkmcnt(0)" ::: "memory");
    __builtin_amdgcn_sched_barrier(0);
    MFMA16(4, 0)
    asm volatile("s_waitcnt vmcnt(4)\n\ts_barrier" ::: "memory");

    // ---- P3: ds_read B(ks1), A m0-3(ks1); stage A-h1 ----
    #pragma unroll
    for (int i = 0; i < 4; ++i) bF[i] = *(const bf16x8*)(base + 16384 + boff[i]);
    #pragma unroll
    for (int i = 0; i < 4; ++i) aF[i] = *(const bf16x8*)(base + 16384 + aoff[i]);
    ld16(A0g + ksrc + 32, nd + 16384);
    ld16(A1g + ksrc + 32, nd + 20480);
    __builtin_amdgcn_s_barrier();
    asm volatile("s_waitcnt lgkmcnt(0)" ::: "memory");
    __builtin_amdgcn_sched_barrier(0);
    MFMA16(0, 1)
    __builtin_amdgcn_s_barrier();

    // ---- P4: ds_read A m4-7(ks1); stage B-h1; MFMA; vmcnt(4) ----
    #pragma unroll
    for (int i = 0; i < 4; ++i) aF[i] = *(const bf16x8*)(base + 16384 + aoff[4 + i]);
    ld16(B0g + ksrc + 32, nd + 24576);
    ld16(B1g + ksrc + 32, nd + 28672);
    __builtin_amdgcn_s_barrier();
    asm volatile("s_waitcnt lgkmcnt(0)" ::: "memory");
    __builtin_amdgcn_sched_barrier(0);
    MFMA16(4, 1)
    asm volatile("s_waitcnt vmcnt(4)\n\ts_barrier" ::: "memory");
  }
  asm volatile("s_waitcnt vmcnt(0)\n\ts_barrier" ::: "memory");
#undef MFMA16

  // ---- epilogue: two half-tiles of 128 rows through LDS (reuses ring space) ----
  int lr = q * 4;
  #pragma unroll
  for (int h = 0; h < 2; ++h) {
    if ((w >> 2) == h) {
      #pragma unroll
      for (int mi = 0; mi < 8; ++mi) {
        #pragma unroll
        for (int ni = 0; ni < 4; ++ni) {
          int cn = wn + ni * 16 + lm;
          float bb = bias[n0 + cn];
          #pragma unroll
          for (int r = 0; r < 4; ++r) {
            int row = mi * 16 + lr + r;
            float v = acc[mi][ni][r] + bb;
            v = v > 0.f ? v : 0.01f * v;            // leaky_relu 0.01
            Sm[row * 256 + cn] = (unsigned short)f2b(v);
          }
        }
      }
    }
    __syncthreads();
    // coalesced 16B stores of this half-tile
    #pragma unroll
    for (int p = 0; p < 8; ++p) {
      int idx = p * 512 + t;
      int rr = idx >> 5;
      int c8 = (idx & 31) * 8;
      uint4 cs = *(const uint4*)(Sm + rr * 256 + c8);
      *(uint4*)(C + (size_t)(m0 + h * 128 + rr) * N + n0 + c8) = cs;
    }
    // fused score partial: 4 threads per row, 64 cols each
    {
      int row = t >> 2, quarter = t & 3;
      int b = (m0 + h * 128) >> 9;
      const uint4* cr = (const uint4*)(Sm + row * 256 + quarter * 64);
      const float4* wr = (const float4*)(wq2 + (size_t)b * 1024 + n0 + quarter * 64);
      float part = 0.f;
      #pragma unroll
      for (int jj = 0; jj < 8; ++jj) {
        uint4 cw = cr[jj];
        float4 w0 = wr[jj * 2], w1 = wr[jj * 2 + 1];
        part += b2f_lo(cw.x) * w0.x + b2f_hi(cw.x) * w0.y;
        part += b2f_lo(cw.y) * w0.z + b2f_hi(cw.y) * w0.w;
        part += b2f_lo(cw.z) * w1.x + b2f_hi(cw.z) * w1.y;
        part += b2f_lo(cw.w) * w1.z + b2f_hi(cw.w) * w1.w;
      }
      part += __shfl_xor(part, 1);
      part += __shfl_xor(part, 2);
      if (quarter == 0) atomicAdd(sc + m0 + h * 128 + row, part);
    }
    __syncthreads();
  }
}

// ---- per-b: finalize scores (mask,cv), softmax, top-32 (single-wave select),
//      gather ctxtail = sum a*tail_f32, gh = sum a*h, asum ----
__global__ __launch_bounds__(256) void topk_ctx_k(const float* __restrict__ sc,
                                                  const float* __restrict__ mask,
                                                  const float* __restrict__ cv,
                                                  const float* __restrict__ xtail,
                                                  const unsigned short* __restrict__ h,
                                                  float* __restrict__ ctxtail, float* __restrict__ gh,
                                                  float* __restrict__ asum) {
  int b = blockIdx.x, t = threadIdx.x;
  __shared__ float sv[512];
  __shared__ float red[256];
  __shared__ float topw[32];
  __shared__ int topi[32];
  float cvb = cv[b];
  float r0 = sc[b * 512 + t], r1 = sc[b * 512 + 256 + t];
  float v0 = (mask[b * 512 + t] > 0.01f) ? (r0 + cvb) : -__builtin_inff();
  float v1 = (mask[b * 512 + 256 + t] > 0.01f) ? (r1 + cvb) : -__builtin_inff();
  sv[t] = v0; sv[t + 256] = v1;
  red[t] = fmaxf(v0, v1);
  __syncthreads();
  for (int s = 128; s > 0; s >>= 1) { if (t < s) red[t] = fmaxf(red[t], red[t + s]); __syncthreads(); }
  float mx = red[0];
  __syncthreads();
  float e0 = expf(v0 - mx), e1 = expf(v1 - mx);
  red[t] = e0 + e1;
  __syncthreads();
  for (int s = 128; s > 0; s >>= 1) { if (t < s) red[t] += red[t + s]; __syncthreads(); }
  float inv = 1.0f / red[0];
  __syncthreads();
  sv[t] = e0 * inv; sv[t + 256] = e1 * inv;
  __syncthreads();
  // single-wave top-32 selection (tie -> lower index, matching lax.top_k stability)
  if (t < 64) {
    float v[8];
    int base = t * 8;
    #pragma unroll
    for (int jj = 0; jj < 8; ++jj) v[jj] = sv[base + jj];
    for (int it = 0; it < 32; ++it) {
      float bv = v[0]; int bj = 0;
      #pragma unroll
      for (int jj = 1; jj < 8; ++jj) if (v[jj] > bv) { bv = v[jj]; bj = jj; }
      int bidx = base + bj;
      #pragma unroll
      for (int off = 32; off > 0; off >>= 1) {
        float ov = __shfl_xor(bv, off);
        int oi = __shfl_xor(bidx, off);
        if (ov > bv || (ov == bv && oi < bidx)) { bv = ov; bidx = oi; }
      }
      if (t == (bidx >> 3)) v[bidx & 7] = -1.0f;
      if (t == 0) { topw[it] = bv; topi[it] = bidx; }
    }
  }
  __syncthreads();
  #pragma unroll
  for (int dd = 0; dd < 4; ++dd) {
    int d = t + dd * 256;
    float at = 0.f, ah = 0.f;
    for (int jj = 0; jj < 32; ++jj) {
      size_t ro = (size_t)(b * 512 + topi[jj]) * 1024 + d;
      at += topw[jj] * xtail[ro];
      ah += topw[jj] * b2f(h[ro]);
    }
    ctxtail[(size_t)b * 1024 + d] = at;
    gh[(size_t)b * 1024 + d] = ah;
  }
  if (t == 0) {
    float s = 0.f;
    for (int jj = 0; jj < 32; ++jj) s += topw[jj];
    asum[b] = s;
  }
}

// ---- out = rawL3 + bltr + pout ----
__global__ void ew2_k(const float* __restrict__ r3, const float* __restrict__ bltr,
                      const float* __restrict__ pout, float* __restrict__ out) {
  int idx = blockIdx.x * 256 + threadIdx.x;
  out[idx] = r3[idx] + bltr[idx & 1023] + pout[idx];
}

extern "C" void kernel_launch(void* const* d_in, const int* in_sizes, int n_in,
                              void* d_out, int out_size, void* d_ws, size_t ws_size,
                              hipStream_t stream) {
  const float* x_head = (const float*)d_in[0];
  const float* x_rel  = (const float*)d_in[1];
  const float* x_tail = (const float*)d_in[2];
  const float* x_mask = (const float*)d_in[3];
  const float* x_img  = (const float*)d_in[4];
  const float* wf1 = (const float*)d_in[5];  const float* bf1 = (const float*)d_in[6];
  const float* wf2 = (const float*)d_in[7];  const float* bf2 = (const float*)d_in[8];
  const float* wk  = (const float*)d_in[9];  const float* bk  = (const float*)d_in[10];
  const float* wv  = (const float*)d_in[11]; const float* bv  = (const float*)d_in[12];
  const float* wp  = (const float*)d_in[13]; const float* bp  = (const float*)d_in[14];
  const float* wiq = (const float*)d_in[15]; const float* biq = (const float*)d_in[16];
  const float* whq = (const float*)d_in[17]; const float* bhq = (const float*)d_in[18];
  const float* wlt = (const float*)d_in[19]; const float* blt = (const float*)d_in[20];
  const float* wli = (const float*)d_in[21]; const float* bli = (const float*)d_in[22];
  const float* wltr= (const float*)d_in[23]; const float* bltr= (const float*)d_in[24];
  const float* wgt = (const float*)d_in[25]; const float* bgt = (const float*)d_in[26];
  const float* wgi = (const float*)d_in[27]; const float* bgi = (const float*)d_in[28];
  float* out = (float*)d_out;
  char* ws = (char*)d_ws;

  // workspace layout (bytes)
  unsigned short* feat = (unsigned short*)(ws);                       // 268435456 (stays live)
  unsigned short* hbuf = (unsigned short*)(ws + 268435456ull);        // 134217728
  unsigned short* wf1t = (unsigned short*)(ws + 402653184ull);        // 4194304
  char* z = ws + 406847488ull;                                        // zeroed region
  float* raw_iq = (float*)(z);
  float* raw_hq = (float*)(z + 524288);
  float* raw_t  = (float*)(z + 1048576);
  float* raw_i  = (float*)(z + 1572864);
  float* raw_tg = (float*)(z + 2097152);
  float* raw_ig = (float*)(z + 2621440);
  float* raw_q  = (float*)(z + 3145728);      // qk = qc @ wk^T
  float* wq2    = (float*)(z + 3670016);      // qk @ wf2^T
  float* rawG   = (float*)(z + 4194304);      // gh @ wf2
  float* rawL1  = (float*)(z + 4718592);
  float* rawL2  = (float*)(z + 5242880);
  float* rawL3  = (float*)(z + 5767168);
  float* sc     = (float*)(z + 6291456);      // 262144 bytes, atomically accumulated scores
  float* qc      = (float*)(ws + 413663232ull);
  float* pout    = (float*)(ws + 414187520ull);
  float* cv      = (float*)(ws + 414711808ull);
  float* ctxtail = (float*)(ws + 414715904ull);
  float* gh      = (float*)(ws + 415240192ull);
  float* asum    = (float*)(ws + 415764480ull);

  // allow 128KB dynamic LDS for the big GEMM (host-side attr, graph-capture safe)
  hipFuncSetAttribute((const void*)gemm256_k,
                      hipFuncAttributeMaxDynamicSharedMemorySize, 131072);

  hipMemsetAsync(z, 0, 6553600, stream);

  // small chain first (inputs only) so qk is ready before cvt_feat's fused tail.qk
  SJobs j6 = {};
  j6.j[0] = SJob{x_img,  wiq, nullptr, nullptr, nullptr, raw_iq, 0, 0};
  j6.j[1] = SJob{x_head, whq, nullptr, nullptr, nullptr, raw_hq, 0, 0};
  j6.j[2] = SJob{x_head, wlt, nullptr, nullptr, nullptr, raw_t,  0, 0};
  j6.j[3] = SJob{x_img,  wli, nullptr, nullptr, nullptr, raw_i,  0, 0};
  j6.j[4] = SJob{x_head, wgt, nullptr, nullptr, nullptr, raw_tg, 0, 0};
  j6.j[5] = SJob{x_img,  wgi, nullptr, nullptr, nullptr, raw_ig, 0, 0};
  sgemm_k<<<dim3(32, 4, 6), 256, 0, stream>>>(j6, 1024);

  ew1_k<<<512, 256, 0, stream>>>(raw_iq, raw_hq, raw_t, raw_i, raw_tg, raw_ig,
                                 biq, bhq, blt, bli, bgt, bgi, qc, pout);

  SJobs jq = {};
  jq.j[0] = SJob{qc, wk, nullptr, nullptr, nullptr, raw_q, 1, 0};   // qk = qc @ wk^T
  sgemm_k<<<dim3(32, 8, 1), 256, 0, stream>>>(jq, 1024);
  jq.j[0] = SJob{raw_q, wf2, nullptr, nullptr, nullptr, wq2, 1, 0}; // wq2 = qk @ wf2^T
  sgemm_k<<<dim3(32, 8, 1), 256, 0, stream>>>(jq, 1024);
  cvec_k<<<128, 64, 0, stream>>>(qc, bk, raw_q, bf2, cv);           // cv = qc·bk + qk·bf2

  cvt_feat_k<<<65536, 256, 0, stream>>>((const float4*)x_tail, (const float4*)x_rel,
                                        (uint4*)feat, raw_q, sc);
  transpose_cvt_k<<<dim3(32, 64), 256, 0, stream>>>(wf1, wf1t, 2048, 1024);

  // h = leaky(feat @ wf1 + bf1); sc += h . wq2
  gemm256_k<<<1024, 512, 131072, stream>>>(feat, wf1t, bf1, wq2, hbuf, sc, 65536, 1024, 2048);

  topk_ctx_k<<<128, 256, 0, stream>>>(sc, x_mask, cv, x_tail, hbuf, ctxtail, gh, asum);

  SJobs jl = {};
  jl.j[0] = SJob{gh, wf2, nullptr, nullptr, nullptr, rawG, 0, 0};        // gh @ wf2
  sgemm_k<<<dim3(32, 8, 1), 256, 0, stream>>>(jl, 1024);
  jl.j[0] = SJob{rawG, wv, bf2, asum, ctxtail, rawL1, 0, 0};             // (ctx_rt) @ wv
  sgemm_k<<<dim3(32, 8, 1), 256, 0, stream>>>(jl, 1024);
  jl.j[0] = SJob{rawL1, wp, bv, asum, nullptr, rawL2, 0, 0};             // (+asum*bv) @ wp
  sgemm_k<<<dim3(32, 8, 1), 256, 0, stream>>>(jl, 1024);
  jl.j[0] = SJob{rawL2, wltr, bp, nullptr, nullptr, rawL3, 0, 0};        // (+bp) @ wltr
  sgemm_k<<<dim3(32, 8, 1), 256, 0, stream>>>(jl, 1024);
  ew2_k<<<512, 256, 0, stream>>>(rawL3, bltr, pout, out);
}